// Round 6
// baseline (424.174 us; speedup 1.0000x reference)
//
#include <hip/hip_runtime.h>
#include <hip/hip_bf16.h>

// Problem constants (match reference)
#define NN 50000
#define EE 800000
#define EP (EE + NN)        // edges + self loops = 850000
#define DIN 128
#define HID 32
#define HEADS 8
#define C1 (HEADS * HID)    // 256
#define DOUT 16
#define NW1 3125            // gemm1/gemm2 waves: 50000/16

typedef __attribute__((ext_vector_type(8))) short short8;   // 8 bf16 (4 VGPRs)
typedef __attribute__((ext_vector_type(4))) float float4v;  // MFMA C/D

__device__ inline unsigned short f2bf(float f) {
    __hip_bfloat16 b = __float2bfloat16(f);
    return *reinterpret_cast<unsigned short*>(&b);
}
__device__ inline float bf2f(unsigned short u) {
    union { unsigned int i; float f; } x;
    x.i = ((unsigned int)u) << 16;
    return x.f;
}
__device__ inline float bflo(unsigned u) {
    union { unsigned int i; float f; } x;
    x.i = u << 16;
    return x.f;
}
__device__ inline float bfhi(unsigned u) {
    union { unsigned int i; float f; } x;
    x.i = u & 0xffff0000u;
    return x.f;
}

// ---------------------------------------------------------------------------
// CSR build: deg init (self loop = 1), count, scan (3 kernels), scatter
// ---------------------------------------------------------------------------
__global__ void k_initdeg(int* __restrict__ deg) {
    int i = blockIdx.x * 256 + threadIdx.x;
    if (i < NN) deg[i] = 1;   // self loop
}

__global__ void k_countdeg(const int* __restrict__ ei, int* __restrict__ deg) {
    int i = blockIdx.x * 256 + threadIdx.x;
    if (i < EE) atomicAdd(&deg[ei[EE + i]], 1);
}

__global__ void k_scan1(const int* __restrict__ deg, int* __restrict__ row_ptr,
                        int* __restrict__ aux) {
    __shared__ int s[1024];
    int t = threadIdx.x;
    int i = blockIdx.x * 1024 + t;
    int v = (i < NN) ? deg[i] : 0;
    int orig = v;
    s[t] = v;
    for (int off = 1; off < 1024; off <<= 1) {
        __syncthreads();
        int u = (t >= off) ? s[t - off] : 0;
        __syncthreads();
        s[t] += u;
    }
    __syncthreads();
    if (i < NN) row_ptr[i] = s[t] - orig;       // exclusive within block
    if (t == 1023) aux[blockIdx.x] = s[t];      // block total
}

// 64-lane shuffle exclusive scan over <=64 block totals (nb = 49)
__global__ void k_scan2(int* __restrict__ aux, int nb) {
    int t = threadIdx.x;   // 64 threads
    int v = (t < nb) ? aux[t] : 0;
    int inc = v;
    #pragma unroll
    for (int off = 1; off < 64; off <<= 1) {
        int u = __shfl_up(inc, off, 64);
        if (t >= off) inc += u;
    }
    if (t < nb) aux[t] = inc - v;
}

__global__ void k_scan3(int* __restrict__ row_ptr, const int* __restrict__ aux,
                        int* __restrict__ wp) {
    int i = blockIdx.x * 256 + threadIdx.x;
    if (i < NN) {
        int v = row_ptr[i] + aux[i >> 10];
        row_ptr[i] = v;
        wp[i] = v;
    }
    if (i == 0) row_ptr[NN] = EP;
}

__global__ void k_scatter(const int* __restrict__ ei, int* __restrict__ wp,
                          int* __restrict__ esrc) {
    int i = blockIdx.x * 256 + threadIdx.x;
    if (i < EE) {
        int s = ei[i];
        int d = ei[EE + i];
        int pos = atomicAdd(&wp[d], 1);
        esrc[pos] = s;
    } else if (i < EP) {
        int n = i - EE;
        int pos = atomicAdd(&wp[n], 1);
        esrc[pos] = n;   // self loop
    }
}

// ---------------------------------------------------------------------------
// prep: va[k][i] (i<8: src-head i, i>=8: dst-head i-8) = per-head compressed
// attention vectors so al1 = x @ va comes out of the same MFMA as h1.
// ---------------------------------------------------------------------------
__global__ void k_prepva(const float* __restrict__ W1, const float* __restrict__ a1s,
                         const float* __restrict__ a1d, float* __restrict__ va) {
    int i = blockIdx.x * 256 + threadIdx.x;   // 128*16
    if (i >= DIN * 16) return;
    int k = i >> 4, idx = i & 15;
    int h = idx & 7;
    const float* av = (idx < 8) ? a1s : a1d;
    float s = 0.f;
    #pragma unroll
    for (int j = 0; j < 32; j++) s += W1[k * C1 + h * 32 + j] * av[h * 32 + j];
    va[i] = s;
}

// ---------------------------------------------------------------------------
// prep: swizzled bf16 A-fragment image for gemm1 (17 tiles: W1^T + va).
// ---------------------------------------------------------------------------
__global__ void k_prepfrag(const float* __restrict__ W1, const float* __restrict__ va,
                           unsigned short* __restrict__ w1frag) {
    int i = blockIdx.x * 256 + threadIdx.x;   // 17*2048 = 34816
    if (i >= 17 * 2048) return;
    int j = i & 7, lane = (i >> 3) & 63, s = (i >> 9) & 3, c = i >> 11;
    int q = lane >> 4, m = lane & 15;
    int k = s * 32 + q * 8 + j;
    float val = (c < 16) ? W1[k * C1 + c * 16 + m] : va[k * 16 + m];
    w1frag[i] = f2bf(val);
}

// ---------------------------------------------------------------------------
// GEMM1 via MFMA (operand-swapped, R5 structure). Epilogue now writes
// HEAD-MAJOR h1h[h][node][32] (tile c -> head c>>1, offset (c&1)*16+quad*4)
// and logits alh[16][node] (rows 0-7 = src head, 8-15 = dst head).
// ---------------------------------------------------------------------------
__global__ __launch_bounds__(256) void k_gemm1(const float* __restrict__ x,
                                               const unsigned short* __restrict__ w1frag,
                                               unsigned short* __restrict__ h1h,
                                               float* __restrict__ alh) {
    int wid = (blockIdx.x * 256 + threadIdx.x) >> 6;
    int lane = threadIdx.x & 63;
    if (wid >= NW1) return;
    int nb = wid * 16;
    int m = lane & 15, quad = lane >> 4;
    const float* xrow = x + (nb + m) * DIN;

    float4v acc[17];
    #pragma unroll
    for (int c = 0; c < 17; c++) acc[c] = (float4v){0.f, 0.f, 0.f, 0.f};

    #pragma unroll
    for (int s = 0; s < 4; s++) {
        float4 f0 = *(const float4*)(xrow + s * 32 + quad * 8);
        float4 f1 = *(const float4*)(xrow + s * 32 + quad * 8 + 4);
        short8 bfrag;
        unsigned short* bp = (unsigned short*)&bfrag;
        bp[0] = f2bf(f0.x); bp[1] = f2bf(f0.y); bp[2] = f2bf(f0.z); bp[3] = f2bf(f0.w);
        bp[4] = f2bf(f1.x); bp[5] = f2bf(f1.y); bp[6] = f2bf(f1.z); bp[7] = f2bf(f1.w);
        const unsigned short* fp = w1frag + (s * 64 + lane) * 8;
        #pragma unroll
        for (int c = 0; c < 17; c++) {
            short8 afrag = *(const short8*)(fp + c * 2048);
            acc[c] = __builtin_amdgcn_mfma_f32_16x16x32_bf16(afrag, bfrag, acc[c], 0, 0, 0);
        }
    }

    int node = nb + m;
    #pragma unroll
    for (int c = 0; c < 16; c++) {
        uint2 pk;
        pk.x = (unsigned)f2bf(acc[c][0]) | ((unsigned)f2bf(acc[c][1]) << 16);
        pk.y = (unsigned)f2bf(acc[c][2]) | ((unsigned)f2bf(acc[c][3]) << 16);
        *(uint2*)(h1h + (c >> 1) * (NN * 32) + node * 32 + (c & 1) * 16 + quad * 4) = pk;
    }
    #pragma unroll
    for (int r = 0; r < 4; r++) {
        alh[(quad * 4 + r) * NN + node] = acc[16][r];
    }
}

// ---------------------------------------------------------------------------
// agg1 (head-partitioned, XCD-pinned): head = blockIdx & 7 so (with %8
// round-robin block->XCD dispatch) each XCD's L2 caches one 3.2 MB head
// slice of h1h. One wave = one (dst node, head). Phase 1: lane e computes
// the edge weight (als[s] + ald). Phase 2: lanes = 4 edge-slots x 16
// channel-pairs, uint (2x bf16) gathers; group-reduce via shfl_xor 16/32.
// Epilogue: bias + ELU, write 32 channels into node-major helu_b.
// ---------------------------------------------------------------------------
__global__ __launch_bounds__(256) void k_agg1(const int* __restrict__ row_ptr,
                                              const int* __restrict__ esrc,
                                              const unsigned short* __restrict__ h1h,
                                              const float* __restrict__ alh,
                                              const float* __restrict__ b1,
                                              unsigned short* __restrict__ helu_b) {
    __shared__ float wbuf[4][64];
    __shared__ int   sbuf[4][64];
    int h = blockIdx.x & 7;
    int chunk = blockIdx.x >> 3;
    int wslot = threadIdx.x >> 6;
    int L = threadIdx.x & 63;
    int d = chunk * 4 + wslot;            // 12500*4 = 50000 exact
    const unsigned short* hsl = h1h + h * (NN * 32);
    const float* als = alh + h * NN;
    float ald = alh[(8 + h) * NN + d];
    int start = row_ptr[d], end = row_ptr[d + 1];
    int g = L >> 4, c2 = L & 15;
    float* wrow = wbuf[wslot];
    int* srow = sbuf[wslot];
    float acc0 = 0.f, acc1 = 0.f, denom = 0.f;

    for (int base = start; base < end; base += 64) {
        int cnt = min(64, end - base);
        int s = d; float w = 0.f;
        if (L < cnt) {
            s = esrc[base + L];
            float e = als[s] + ald;
            e = e > 0.f ? e : 0.2f * e;
            w = __expf(e);
        }
        srow[L] = s;
        wrow[L] = w;
        int cnt4 = (cnt + 3) & ~3;
        for (int i = 0; i < cnt4; i += 4) {
            int ss = srow[i + g];
            float ww = wrow[i + g];
            unsigned v = *(const unsigned*)(hsl + ss * 32 + c2 * 2);
            acc0 += ww * bflo(v);
            acc1 += ww * bfhi(v);
            denom += ww;
        }
    }
    acc0 += __shfl_xor(acc0, 16, 64); acc0 += __shfl_xor(acc0, 32, 64);
    acc1 += __shfl_xor(acc1, 16, 64); acc1 += __shfl_xor(acc1, 32, 64);
    denom += __shfl_xor(denom, 16, 64); denom += __shfl_xor(denom, 32, 64);
    if (L < 16) {
        float inv = 1.0f / (denom + 1e-16f);
        float2 bv = *(const float2*)(b1 + h * 32 + c2 * 2);
        float o0 = acc0 * inv + bv.x;
        float o1 = acc1 * inv + bv.y;
        o0 = o0 > 0.f ? o0 : __expf(o0) - 1.0f;
        o1 = o1 > 0.f ? o1 : __expf(o1) - 1.0f;
        unsigned pk = (unsigned)f2bf(o0) | ((unsigned)f2bf(o1) << 16);
        *(unsigned*)(helu_b + d * C1 + h * 32 + c2 * 2) = pk;
    }
}

// ---------------------------------------------------------------------------
// W2 cast fp32 -> bf16 (4096 elements), keeps [k][c] row-major layout
// ---------------------------------------------------------------------------
__global__ void k_prepw2(const float* __restrict__ W2, unsigned short* __restrict__ W2b) {
    int i = blockIdx.x * 256 + threadIdx.x;
    if (i < C1 * DOUT) W2b[i] = f2bf(W2[i]);
}

// ---------------------------------------------------------------------------
// GEMM2 via MFMA 16x16x32 bf16 + fused al2 epilogue (unchanged).
// ---------------------------------------------------------------------------
__global__ __launch_bounds__(256) void k_gemm2(const unsigned short* __restrict__ helu_b,
                                               const unsigned short* __restrict__ W2b,
                                               const float* __restrict__ a2s,
                                               const float* __restrict__ a2d,
                                               unsigned short* __restrict__ h2b,
                                               float* __restrict__ al2s,
                                               float* __restrict__ al2d) {
    int wid = (blockIdx.x * 256 + threadIdx.x) >> 6;
    int lane = threadIdx.x & 63;
    int nb = wid * 16;
    if (nb >= NN) return;
    int m = lane & 15, quad = lane >> 4;

    short8 bfrag[8];
    #pragma unroll
    for (int s = 0; s < 8; s++) {
        #pragma unroll
        for (int j = 0; j < 8; j++) {
            ((short*)&bfrag[s])[j] = (short)W2b[(s * 32 + quad * 8 + j) * DOUT + m];
        }
    }

    float4v acc = {0.f, 0.f, 0.f, 0.f};
    const unsigned short* arow = helu_b + (nb + m) * C1 + quad * 8;
    #pragma unroll
    for (int s = 0; s < 8; s++) {
        short8 afrag = *(const short8*)(arow + s * 32);
        acc = __builtin_amdgcn_mfma_f32_16x16x32_bf16(afrag, bfrag[s], acc, 0, 0, 0);
    }

    float as_c = a2s[m], ad_c = a2d[m];
    #pragma unroll
    for (int r = 0; r < 4; r++) {
        int node = nb + quad * 4 + r;
        float val = acc[r];
        h2b[node * DOUT + m] = f2bf(val);
        float ps = val * as_c;
        float pd = val * ad_c;
        ps += __shfl_xor(ps, 1, 64); ps += __shfl_xor(ps, 2, 64);
        ps += __shfl_xor(ps, 4, 64); ps += __shfl_xor(ps, 8, 64);
        pd += __shfl_xor(pd, 1, 64); pd += __shfl_xor(pd, 2, 64);
        pd += __shfl_xor(pd, 4, 64); pd += __shfl_xor(pd, 8, 64);
        if (m == 0) {
            al2s[node] = ps;
            al2d[node] = pd;
        }
    }
}

// ---------------------------------------------------------------------------
// agg2 + bias + log_softmax: one wave per node, two-phase (unchanged).
// ---------------------------------------------------------------------------
__global__ __launch_bounds__(256) void k_agg2(const int* __restrict__ row_ptr,
                                              const int* __restrict__ esrc,
                                              const unsigned short* __restrict__ h2b,
                                              const float* __restrict__ al2s,
                                              const float* __restrict__ al2d,
                                              const float* __restrict__ b2,
                                              float* __restrict__ out) {
    __shared__ float wbuf2[4][64];
    __shared__ int   sbuf2[4][64];
    int wslot = threadIdx.x >> 6;
    int L = threadIdx.x & 63;
    int n = (blockIdx.x * 256 + threadIdx.x) >> 6;
    if (n >= NN) return;
    int c = L & 15, g = L >> 4;
    int start = row_ptr[n], end = row_ptr[n + 1];
    float ald = al2d[n];
    float* wrow = wbuf2[wslot];
    int* srow = sbuf2[wslot];
    float acc = 0.f, denom = 0.f;

    for (int base = start; base < end; base += 64) {
        int cnt = min(64, end - base);
        int s = n; float w = 0.f;
        if (L < cnt) {
            s = esrc[base + L];
            float e = al2s[s] + ald;
            e = e > 0.f ? e : 0.2f * e;
            w = __expf(e);
        }
        srow[L] = s;
        wrow[L] = w;
        int cnt4 = (cnt + 3) & ~3;
        for (int i = 0; i < cnt4; i += 4) {
            int idx = i + g;
            int ss = srow[idx];
            float ww = wrow[idx];
            float v = bf2f(h2b[ss * DOUT + c]);
            acc += ww * v;
            denom += ww;
        }
    }
    acc += __shfl_xor(acc, 16, 64);   acc += __shfl_xor(acc, 32, 64);
    denom += __shfl_xor(denom, 16, 64); denom += __shfl_xor(denom, 32, 64);
    float val = acc / (denom + 1e-16f) + b2[c];
    float m = val;
    #pragma unroll
    for (int mm = 1; mm < 16; mm <<= 1) m = fmaxf(m, __shfl_xor(m, mm, 64));
    float ex = __expf(val - m);
    float se = ex;
    #pragma unroll
    for (int mm = 1; mm < 16; mm <<= 1) se += __shfl_xor(se, mm, 64);
    if (L < 16) out[n * DOUT + c] = val - m - __logf(se);
}

// ---------------------------------------------------------------------------
extern "C" void kernel_launch(void* const* d_in, const int* in_sizes, int n_in,
                              void* d_out, int out_size, void* d_ws, size_t ws_size,
                              hipStream_t stream) {
    const float* x   = (const float*)d_in[0];
    const int*   ei  = (const int*)d_in[1];
    const float* W1  = (const float*)d_in[2];
    const float* a1s = (const float*)d_in[3];
    const float* a1d = (const float*)d_in[4];
    const float* b1  = (const float*)d_in[5];
    const float* W2  = (const float*)d_in[6];
    const float* a2s = (const float*)d_in[7];
    const float* a2d = (const float*)d_in[8];
    const float* b2  = (const float*)d_in[9];
    float* outp = (float*)d_out;

    // workspace layout
    unsigned short* h1h    = (unsigned short*)d_ws;      // 8 * N * 32 bf16 (head-major)
    unsigned short* helu_b = h1h + NN * C1;              // N*256 bf16 (node-major)
    unsigned short* h2b    = helu_b + NN * C1;           // N*16 bf16
    unsigned short* W2b    = h2b + NN * DOUT;            // 4096 bf16
    unsigned short* w1frag = W2b + C1 * DOUT;            // 34816 bf16
    float* va    = (float*)(w1frag + 17 * 2048);         // 2048
    float* alh   = va + DIN * 16;                        // 16 * N  (0-7 src, 8-15 dst)
    float* al2sb = alh + 16 * NN;                        // N
    float* al2db = al2sb + NN;                           // N
    int* deg     = (int*)(al2db + NN);                   // N
    int* row_ptr = deg + NN;                             // N+1
    int* wp      = row_ptr + NN + 1;                     // N
    int* esrc    = wp + NN;                              // EP
    int* aux     = esrc + EP;                            // 64

    const int nscan = (NN + 1023) / 1024;   // 49

    k_initdeg<<<(NN + 255) / 256, 256, 0, stream>>>(deg);
    k_countdeg<<<(EE + 255) / 256, 256, 0, stream>>>(ei, deg);
    k_scan1<<<nscan, 1024, 0, stream>>>(deg, row_ptr, aux);
    k_scan2<<<1, 64, 0, stream>>>(aux, nscan);
    k_scan3<<<(NN + 255) / 256, 256, 0, stream>>>(row_ptr, aux, wp);
    k_scatter<<<(EP + 255) / 256, 256, 0, stream>>>(ei, wp, esrc);

    k_prepva<<<(DIN * 16 + 255) / 256, 256, 0, stream>>>(W1, a1s, a1d, va);
    k_prepfrag<<<(17 * 2048 + 255) / 256, 256, 0, stream>>>(W1, va, w1frag);
    k_gemm1<<<(NW1 * 64 + 255) / 256, 256, 0, stream>>>(x, w1frag, h1h, alh);
    // 12500 node-chunks x 8 heads; head = blockIdx & 7 (XCD swizzle)
    k_agg1<<<12500 * 8, 256, 0, stream>>>(row_ptr, esrc, h1h, alh, b1, helu_b);

    k_prepw2<<<(C1 * DOUT + 255) / 256, 256, 0, stream>>>(W2, W2b);
    k_gemm2<<<(NW1 * 64 + 255) / 256, 256, 0, stream>>>(helu_b, W2b, a2s, a2d, h2b, al2sb, al2db);
    k_agg2<<<(NN * 64 + 255) / 256, 256, 0, stream>>>(row_ptr, esrc, h2b, al2sb, al2db, b2, outp);
}

// Round 7
// 315.279 us; speedup vs baseline: 1.3454x; 1.3454x over previous
//
#include <hip/hip_runtime.h>
#include <hip/hip_bf16.h>

// Problem constants (match reference)
#define NN 50000
#define EE 800000
#define EP (EE + NN)        // edges + self loops = 850000
#define DIN 128
#define HID 32
#define HEADS 8
#define C1 (HEADS * HID)    // 256
#define DOUT 16
#define NW1 3125            // gemm1/gemm2 waves: 50000/16

typedef __attribute__((ext_vector_type(8))) short short8;   // 8 bf16 (4 VGPRs)
typedef __attribute__((ext_vector_type(4))) float float4v;  // MFMA C/D

__device__ inline unsigned short f2bf(float f) {
    __hip_bfloat16 b = __float2bfloat16(f);
    return *reinterpret_cast<unsigned short*>(&b);
}
__device__ inline float bf2f(unsigned short u) {
    union { unsigned int i; float f; } x;
    x.i = ((unsigned int)u) << 16;
    return x.f;
}
__device__ inline float bflo(unsigned u) {
    union { unsigned int i; float f; } x;
    x.i = u << 16;
    return x.f;
}
__device__ inline float bfhi(unsigned u) {
    union { unsigned int i; float f; } x;
    x.i = u & 0xffff0000u;
    return x.f;
}

// ---------------------------------------------------------------------------
// CSR build
// ---------------------------------------------------------------------------
__global__ void k_initdeg(int* __restrict__ deg) {
    int i = blockIdx.x * 256 + threadIdx.x;
    if (i < NN) deg[i] = 1;   // self loop
}

__global__ void k_countdeg(const int* __restrict__ ei, int* __restrict__ deg) {
    int i = blockIdx.x * 256 + threadIdx.x;
    if (i < EE) atomicAdd(&deg[ei[EE + i]], 1);
}

__global__ void k_scan1(const int* __restrict__ deg, int* __restrict__ row_ptr,
                        int* __restrict__ aux) {
    __shared__ int s[1024];
    int t = threadIdx.x;
    int i = blockIdx.x * 1024 + t;
    int v = (i < NN) ? deg[i] : 0;
    int orig = v;
    s[t] = v;
    for (int off = 1; off < 1024; off <<= 1) {
        __syncthreads();
        int u = (t >= off) ? s[t - off] : 0;
        __syncthreads();
        s[t] += u;
    }
    __syncthreads();
    if (i < NN) row_ptr[i] = s[t] - orig;       // exclusive within block
    if (t == 1023) aux[blockIdx.x] = s[t];      // block total
}

// 64-lane shuffle exclusive scan over <=64 block totals (nb = 49)
__global__ void k_scan2(int* __restrict__ aux, int nb) {
    int t = threadIdx.x;   // 64 threads
    int v = (t < nb) ? aux[t] : 0;
    int inc = v;
    #pragma unroll
    for (int off = 1; off < 64; off <<= 1) {
        int u = __shfl_up(inc, off, 64);
        if (t >= off) inc += u;
    }
    if (t < nb) aux[t] = inc - v;
}

__global__ void k_scan3(int* __restrict__ row_ptr, const int* __restrict__ aux,
                        int* __restrict__ wp) {
    int i = blockIdx.x * 256 + threadIdx.x;
    if (i < NN) {
        int v = row_ptr[i] + aux[i >> 10];
        row_ptr[i] = v;
        wp[i] = v;
    }
    if (i == 0) row_ptr[NN] = EP;
}

__global__ void k_scatter(const int* __restrict__ ei, int* __restrict__ wp,
                          int* __restrict__ esrc) {
    int i = blockIdx.x * 256 + threadIdx.x;
    if (i < EE) {
        int s = ei[i];
        int d = ei[EE + i];
        int pos = atomicAdd(&wp[d], 1);
        esrc[pos] = s;
    } else if (i < EP) {
        int n = i - EE;
        int pos = atomicAdd(&wp[n], 1);
        esrc[pos] = n;   // self loop
    }
}

// ---------------------------------------------------------------------------
// prep: va[k][i] (i<8: src-head i, i>=8: dst-head i-8)
// ---------------------------------------------------------------------------
__global__ void k_prepva(const float* __restrict__ W1, const float* __restrict__ a1s,
                         const float* __restrict__ a1d, float* __restrict__ va) {
    int i = blockIdx.x * 256 + threadIdx.x;   // 128*16
    if (i >= DIN * 16) return;
    int k = i >> 4, idx = i & 15;
    int h = idx & 7;
    const float* av = (idx < 8) ? a1s : a1d;
    float s = 0.f;
    #pragma unroll
    for (int j = 0; j < 32; j++) s += W1[k * C1 + h * 32 + j] * av[h * 32 + j];
    va[i] = s;
}

// ---------------------------------------------------------------------------
// prep: gemm1 A-fragment image (17 tiles) + W2 bf16 cast, one kernel.
// ---------------------------------------------------------------------------
__global__ void k_prepfw(const float* __restrict__ W1, const float* __restrict__ va,
                         const float* __restrict__ W2,
                         unsigned short* __restrict__ w1frag,
                         unsigned short* __restrict__ W2b) {
    int i = blockIdx.x * 256 + threadIdx.x;
    if (i < 17 * 2048) {
        int j = i & 7, lane = (i >> 3) & 63, s = (i >> 9) & 3, c = i >> 11;
        int q = lane >> 4, m = lane & 15;
        int k = s * 32 + q * 8 + j;
        float val = (c < 16) ? W1[k * C1 + c * 16 + m] : va[k * 16 + m];
        w1frag[i] = f2bf(val);
    } else if (i < 17 * 2048 + C1 * DOUT) {
        int j = i - 17 * 2048;
        W2b[j] = f2bf(W2[j]);
    }
}

// ---------------------------------------------------------------------------
// GEMM1 via MFMA (operand-swapped). All 8 x-loads hoisted upfront for max
// overlap. Epilogue: h1 split in two half-tables h1A (heads 0-3) / h1B
// (heads 4-7), rows 128 ch = 256 B; al1sd[node][16] float4 stores.
// ---------------------------------------------------------------------------
__global__ __launch_bounds__(256) void k_gemm1(const float* __restrict__ x,
                                               const unsigned short* __restrict__ w1frag,
                                               unsigned short* __restrict__ h1A,
                                               unsigned short* __restrict__ h1B,
                                               float* __restrict__ al1sd) {
    int wid = (blockIdx.x * 256 + threadIdx.x) >> 6;
    int lane = threadIdx.x & 63;
    if (wid >= NW1) return;
    int nb = wid * 16;
    int m = lane & 15, quad = lane >> 4;
    const float* xrow = x + (nb + m) * DIN;

    // hoist all x loads (independent, fill MRQ early)
    float4 xf[8];
    #pragma unroll
    for (int s = 0; s < 4; s++) {
        xf[2 * s]     = *(const float4*)(xrow + s * 32 + quad * 8);
        xf[2 * s + 1] = *(const float4*)(xrow + s * 32 + quad * 8 + 4);
    }
    short8 bfr[4];
    #pragma unroll
    for (int s = 0; s < 4; s++) {
        unsigned short* bp = (unsigned short*)&bfr[s];
        float4 f0 = xf[2 * s], f1 = xf[2 * s + 1];
        bp[0] = f2bf(f0.x); bp[1] = f2bf(f0.y); bp[2] = f2bf(f0.z); bp[3] = f2bf(f0.w);
        bp[4] = f2bf(f1.x); bp[5] = f2bf(f1.y); bp[6] = f2bf(f1.z); bp[7] = f2bf(f1.w);
    }

    float4v acc[17];
    #pragma unroll
    for (int c = 0; c < 17; c++) acc[c] = (float4v){0.f, 0.f, 0.f, 0.f};

    #pragma unroll
    for (int s = 0; s < 4; s++) {
        const unsigned short* fp = w1frag + (s * 64 + lane) * 8;
        #pragma unroll
        for (int c = 0; c < 17; c++) {
            short8 afrag = *(const short8*)(fp + c * 2048);
            acc[c] = __builtin_amdgcn_mfma_f32_16x16x32_bf16(afrag, bfr[s], acc[c], 0, 0, 0);
        }
    }

    int node = nb + m;
    #pragma unroll
    for (int c = 0; c < 16; c++) {
        int head = c >> 1;
        unsigned short* tab = (head < 4) ? h1A : h1B;
        int col = (head & 3) * 32 + (c & 1) * 16 + quad * 4;
        uint2 pk;
        pk.x = (unsigned)f2bf(acc[c][0]) | ((unsigned)f2bf(acc[c][1]) << 16);
        pk.y = (unsigned)f2bf(acc[c][2]) | ((unsigned)f2bf(acc[c][3]) << 16);
        *(uint2*)(tab + node * 128 + col) = pk;
    }
    *(float4*)(al1sd + node * 16 + quad * 4) =
        make_float4(acc[16][0], acc[16][1], acc[16][2], acc[16][3]);
}

// ---------------------------------------------------------------------------
// agg1 v7: wave = (dst, head-group hg). hg = (blockIdx>>2)&1 so with the %8
// round-robin block->XCD dispatch, hg=0 lands on XCDs 0-3 (caching the
// 12.8 MB h1A) and hg=1 on XCDs 4-7 (h1B) -- per-XCD working set halved vs
// R5 while keeping R5's coarse wave-per-dst efficiency (uint4 = 256 B/edge
// gather, 4 edges in flight). Phase 1: lane e computes the 4 head-weights
// of edge e. Phase 2: lanes = 4 edge-slots (g) x 16 uint4-chunks (c2).
// ---------------------------------------------------------------------------
__global__ __launch_bounds__(256) void k_agg1(const int* __restrict__ row_ptr,
                                              const int* __restrict__ esrc,
                                              const unsigned short* __restrict__ h1A,
                                              const unsigned short* __restrict__ h1B,
                                              const float* __restrict__ al1sd,
                                              const float* __restrict__ b1,
                                              unsigned short* __restrict__ helu_b) {
    __shared__ float wbuf[4][64 * 4];
    __shared__ int   sbuf[4][64];
    int b = blockIdx.x;
    int hg = (b >> 2) & 1;
    int grp = (b >> 3) * 4 + (b & 3);     // 0..12499 within head-group
    int wslot = threadIdx.x >> 6;
    int L = threadIdx.x & 63;
    int d = grp * 4 + wslot;              // 0..49999
    const unsigned short* tab = hg ? h1B : h1A;
    int start = row_ptr[d], end = row_ptr[d + 1];
    float4 ald = *(const float4*)(al1sd + d * 16 + 8 + hg * 4);
    int g = L >> 4, c2 = L & 15;
    int hloc = c2 >> 2;                   // head-in-group for my channels
    float* wrow = wbuf[wslot];
    int* srow = sbuf[wslot];
    float a0 = 0.f, a1 = 0.f, a2 = 0.f, a3 = 0.f;
    float a4 = 0.f, a5 = 0.f, a6 = 0.f, a7 = 0.f;
    float den = 0.f;

    for (int base = start; base < end; base += 64) {
        int cnt = min(64, end - base);
        // phase 1: lane e -> 4 head-weights of edge e
        int s = d;
        float w0 = 0.f, w1 = 0.f, w2 = 0.f, w3 = 0.f;
        if (L < cnt) {
            s = esrc[base + L];
            float4 as = *(const float4*)(al1sd + s * 16 + hg * 4);
            float e;
            e = as.x + ald.x; e = e > 0.f ? e : 0.2f * e; w0 = __expf(e);
            e = as.y + ald.y; e = e > 0.f ? e : 0.2f * e; w1 = __expf(e);
            e = as.z + ald.z; e = e > 0.f ? e : 0.2f * e; w2 = __expf(e);
            e = as.w + ald.w; e = e > 0.f ? e : 0.2f * e; w3 = __expf(e);
        }
        srow[L] = s;
        *(float4*)&wrow[L * 4] = make_float4(w0, w1, w2, w3);
        // phase 2: 4 edges/iter, 256 B/edge via 16 x uint4
        int cnt4 = (cnt + 3) & ~3;
        for (int i = 0; i < cnt4; i += 4) {
            int ss = srow[i + g];
            float ww = wrow[(i + g) * 4 + hloc];
            uint4 v = *(const uint4*)(tab + ss * 128 + c2 * 8);
            a0 += ww * bflo(v.x); a1 += ww * bfhi(v.x);
            a2 += ww * bflo(v.y); a3 += ww * bfhi(v.y);
            a4 += ww * bflo(v.z); a5 += ww * bfhi(v.z);
            a6 += ww * bflo(v.w); a7 += ww * bfhi(v.w);
            den += ww;
        }
    }
    // reduce over the 4 edge-slots (xor flips g bits, keeps c2)
    a0 += __shfl_xor(a0, 16, 64); a0 += __shfl_xor(a0, 32, 64);
    a1 += __shfl_xor(a1, 16, 64); a1 += __shfl_xor(a1, 32, 64);
    a2 += __shfl_xor(a2, 16, 64); a2 += __shfl_xor(a2, 32, 64);
    a3 += __shfl_xor(a3, 16, 64); a3 += __shfl_xor(a3, 32, 64);
    a4 += __shfl_xor(a4, 16, 64); a4 += __shfl_xor(a4, 32, 64);
    a5 += __shfl_xor(a5, 16, 64); a5 += __shfl_xor(a5, 32, 64);
    a6 += __shfl_xor(a6, 16, 64); a6 += __shfl_xor(a6, 32, 64);
    a7 += __shfl_xor(a7, 16, 64); a7 += __shfl_xor(a7, 32, 64);
    den += __shfl_xor(den, 16, 64); den += __shfl_xor(den, 32, 64);
    if (L < 16) {
        float inv = 1.0f / (den + 1e-16f);
        const float* bp = b1 + hg * 128 + c2 * 8;
        float4 bv0 = *(const float4*)bp;
        float4 bv1 = *(const float4*)(bp + 4);
        float o0 = a0 * inv + bv0.x, o1 = a1 * inv + bv0.y;
        float o2 = a2 * inv + bv0.z, o3 = a3 * inv + bv0.w;
        float o4 = a4 * inv + bv1.x, o5 = a5 * inv + bv1.y;
        float o6 = a6 * inv + bv1.z, o7 = a7 * inv + bv1.w;
        o0 = o0 > 0.f ? o0 : __expf(o0) - 1.0f;
        o1 = o1 > 0.f ? o1 : __expf(o1) - 1.0f;
        o2 = o2 > 0.f ? o2 : __expf(o2) - 1.0f;
        o3 = o3 > 0.f ? o3 : __expf(o3) - 1.0f;
        o4 = o4 > 0.f ? o4 : __expf(o4) - 1.0f;
        o5 = o5 > 0.f ? o5 : __expf(o5) - 1.0f;
        o6 = o6 > 0.f ? o6 : __expf(o6) - 1.0f;
        o7 = o7 > 0.f ? o7 : __expf(o7) - 1.0f;
        uint4 pk;
        pk.x = (unsigned)f2bf(o0) | ((unsigned)f2bf(o1) << 16);
        pk.y = (unsigned)f2bf(o2) | ((unsigned)f2bf(o3) << 16);
        pk.z = (unsigned)f2bf(o4) | ((unsigned)f2bf(o5) << 16);
        pk.w = (unsigned)f2bf(o6) | ((unsigned)f2bf(o7) << 16);
        *(uint4*)(helu_b + d * C1 + hg * 128 + c2 * 8) = pk;
    }
}

// ---------------------------------------------------------------------------
// GEMM2 via MFMA 16x16x32 bf16 + fused al2 epilogue (unchanged).
// ---------------------------------------------------------------------------
__global__ __launch_bounds__(256) void k_gemm2(const unsigned short* __restrict__ helu_b,
                                               const unsigned short* __restrict__ W2b,
                                               const float* __restrict__ a2s,
                                               const float* __restrict__ a2d,
                                               unsigned short* __restrict__ h2b,
                                               float* __restrict__ al2s,
                                               float* __restrict__ al2d) {
    int wid = (blockIdx.x * 256 + threadIdx.x) >> 6;
    int lane = threadIdx.x & 63;
    int nb = wid * 16;
    if (nb >= NN) return;
    int m = lane & 15, quad = lane >> 4;

    short8 bfrag[8];
    #pragma unroll
    for (int s = 0; s < 8; s++) {
        #pragma unroll
        for (int j = 0; j < 8; j++) {
            ((short*)&bfrag[s])[j] = (short)W2b[(s * 32 + quad * 8 + j) * DOUT + m];
        }
    }

    float4v acc = {0.f, 0.f, 0.f, 0.f};
    const unsigned short* arow = helu_b + (nb + m) * C1 + quad * 8;
    #pragma unroll
    for (int s = 0; s < 8; s++) {
        short8 afrag = *(const short8*)(arow + s * 32);
        acc = __builtin_amdgcn_mfma_f32_16x16x32_bf16(afrag, bfrag[s], acc, 0, 0, 0);
    }

    float as_c = a2s[m], ad_c = a2d[m];
    #pragma unroll
    for (int r = 0; r < 4; r++) {
        int node = nb + quad * 4 + r;
        float val = acc[r];
        h2b[node * DOUT + m] = f2bf(val);
        float ps = val * as_c;
        float pd = val * ad_c;
        ps += __shfl_xor(ps, 1, 64); ps += __shfl_xor(ps, 2, 64);
        ps += __shfl_xor(ps, 4, 64); ps += __shfl_xor(ps, 8, 64);
        pd += __shfl_xor(pd, 1, 64); pd += __shfl_xor(pd, 2, 64);
        pd += __shfl_xor(pd, 4, 64); pd += __shfl_xor(pd, 8, 64);
        if (m == 0) {
            al2s[node] = ps;
            al2d[node] = pd;
        }
    }
}

// ---------------------------------------------------------------------------
// agg2 + bias + log_softmax (unchanged two-phase).
// ---------------------------------------------------------------------------
__global__ __launch_bounds__(256) void k_agg2(const int* __restrict__ row_ptr,
                                              const int* __restrict__ esrc,
                                              const unsigned short* __restrict__ h2b,
                                              const float* __restrict__ al2s,
                                              const float* __restrict__ al2d,
                                              const float* __restrict__ b2,
                                              float* __restrict__ out) {
    __shared__ float wbuf2[4][64];
    __shared__ int   sbuf2[4][64];
    int wslot = threadIdx.x >> 6;
    int L = threadIdx.x & 63;
    int n = (blockIdx.x * 256 + threadIdx.x) >> 6;
    if (n >= NN) return;
    int c = L & 15, g = L >> 4;
    int start = row_ptr[n], end = row_ptr[n + 1];
    float ald = al2d[n];
    float* wrow = wbuf2[wslot];
    int* srow = sbuf2[wslot];
    float acc = 0.f, denom = 0.f;

    for (int base = start; base < end; base += 64) {
        int cnt = min(64, end - base);
        int s = n; float w = 0.f;
        if (L < cnt) {
            s = esrc[base + L];
            float e = al2s[s] + ald;
            e = e > 0.f ? e : 0.2f * e;
            w = __expf(e);
        }
        srow[L] = s;
        wrow[L] = w;
        int cnt4 = (cnt + 3) & ~3;
        for (int i = 0; i < cnt4; i += 4) {
            int idx = i + g;
            int ss = srow[idx];
            float ww = wrow[idx];
            float v = bf2f(h2b[ss * DOUT + c]);
            acc += ww * v;
            denom += ww;
        }
    }
    acc += __shfl_xor(acc, 16, 64);   acc += __shfl_xor(acc, 32, 64);
    denom += __shfl_xor(denom, 16, 64); denom += __shfl_xor(denom, 32, 64);
    float val = acc / (denom + 1e-16f) + b2[c];
    float m = val;
    #pragma unroll
    for (int mm = 1; mm < 16; mm <<= 1) m = fmaxf(m, __shfl_xor(m, mm, 64));
    float ex = __expf(val - m);
    float se = ex;
    #pragma unroll
    for (int mm = 1; mm < 16; mm <<= 1) se += __shfl_xor(se, mm, 64);
    if (L < 16) out[n * DOUT + c] = val - m - __logf(se);
}

// ---------------------------------------------------------------------------
extern "C" void kernel_launch(void* const* d_in, const int* in_sizes, int n_in,
                              void* d_out, int out_size, void* d_ws, size_t ws_size,
                              hipStream_t stream) {
    const float* x   = (const float*)d_in[0];
    const int*   ei  = (const int*)d_in[1];
    const float* W1  = (const float*)d_in[2];
    const float* a1s = (const float*)d_in[3];
    const float* a1d = (const float*)d_in[4];
    const float* b1  = (const float*)d_in[5];
    const float* W2  = (const float*)d_in[6];
    const float* a2s = (const float*)d_in[7];
    const float* a2d = (const float*)d_in[8];
    const float* b2  = (const float*)d_in[9];
    float* outp = (float*)d_out;

    // workspace layout
    unsigned short* h1A    = (unsigned short*)d_ws;      // N*128 bf16 (heads 0-3)
    unsigned short* h1B    = h1A + NN * 128;             // N*128 bf16 (heads 4-7)
    unsigned short* helu_b = h1B + NN * 128;             // N*256 bf16 (node-major)
    unsigned short* h2b    = helu_b + NN * C1;           // N*16 bf16
    unsigned short* W2b    = h2b + NN * DOUT;            // 4096 bf16
    unsigned short* w1frag = W2b + C1 * DOUT;            // 34816 bf16
    float* va    = (float*)(w1frag + 17 * 2048);         // 2048
    float* al1sd = va + DIN * 16;                        // N*16 (0-7 src, 8-15 dst)
    float* al2sb = al1sd + NN * 16;                      // N
    float* al2db = al2sb + NN;                           // N
    int* deg     = (int*)(al2db + NN);                   // N
    int* row_ptr = deg + NN;                             // N+1
    int* wp      = row_ptr + NN + 1;                     // N
    int* esrc    = wp + NN;                              // EP
    int* aux     = esrc + EP;                            // 64

    const int nscan = (NN + 1023) / 1024;   // 49

    k_initdeg<<<(NN + 255) / 256, 256, 0, stream>>>(deg);
    k_countdeg<<<(EE + 255) / 256, 256, 0, stream>>>(ei, deg);
    k_scan1<<<nscan, 1024, 0, stream>>>(deg, row_ptr, aux);
    k_scan2<<<1, 64, 0, stream>>>(aux, nscan);
    k_scan3<<<(NN + 255) / 256, 256, 0, stream>>>(row_ptr, aux, wp);
    k_scatter<<<(EP + 255) / 256, 256, 0, stream>>>(ei, wp, esrc);

    k_prepva<<<(DIN * 16 + 255) / 256, 256, 0, stream>>>(W1, a1s, a1d, va);
    k_prepfw<<<(17 * 2048 + C1 * DOUT + 255) / 256, 256, 0, stream>>>(W1, va, W2, w1frag, W2b);
    k_gemm1<<<(NW1 * 64 + 255) / 256, 256, 0, stream>>>(x, w1frag, h1A, h1B, al1sd);
    // 25000 blocks: hg = (b>>2)&1 -> XCD-pinned half-tables
    k_agg1<<<25000, 256, 0, stream>>>(row_ptr, esrc, h1A, h1B, al1sd, b1, helu_b);

    k_gemm2<<<(NW1 * 64 + 255) / 256, 256, 0, stream>>>(helu_b, W2b, a2s, a2d, h2b, al2sb, al2db);
    k_agg2<<<(NN * 64 + 255) / 256, 256, 0, stream>>>(row_ptr, esrc, h2b, al2sb, al2db, b2, outp);
}

// Round 8
// 294.312 us; speedup vs baseline: 1.4412x; 1.0712x over previous
//
#include <hip/hip_runtime.h>
#include <hip/hip_bf16.h>

// Problem constants (match reference)
#define NN 50000
#define EE 800000
#define EP (EE + NN)        // edges + self loops = 850000
#define DIN 128
#define HID 32
#define HEADS 8
#define C1 (HEADS * HID)    // 256
#define DOUT 16
#define NW1 3125            // gemm1/gemm2 waves: 50000/16
#define NSCAN 49            // ceil(50000/1024)

typedef __attribute__((ext_vector_type(8))) short short8;   // 8 bf16 (4 VGPRs)
typedef __attribute__((ext_vector_type(4))) float float4v;  // MFMA C/D

__device__ inline unsigned short f2bf(float f) {
    __hip_bfloat16 b = __float2bfloat16(f);
    return *reinterpret_cast<unsigned short*>(&b);
}
__device__ inline float bf2f(unsigned short u) {
    union { unsigned int i; float f; } x;
    x.i = ((unsigned int)u) << 16;
    return x.f;
}
__device__ inline float bflo(unsigned u) {
    union { unsigned int i; float f; } x;
    x.i = u << 16;
    return x.f;
}
__device__ inline float bfhi(unsigned u) {
    union { unsigned int i; float f; } x;
    x.i = u & 0xffff0000u;
    return x.f;
}

// ---------------------------------------------------------------------------
// CSR build (deg zeroed via hipMemsetAsync; self loop folded as +1 in scan1)
// ---------------------------------------------------------------------------
__global__ void k_countdeg(const int* __restrict__ ei, int* __restrict__ deg) {
    int i = blockIdx.x * 256 + threadIdx.x;
    if (i < EE) atomicAdd(&deg[ei[EE + i]], 1);
}

// shfl-based block scan (1024 thr = 16 waves); v = deg[i]+1 (self loop)
__global__ __launch_bounds__(1024) void k_scan1(const int* __restrict__ deg,
                                                int* __restrict__ row_ptr,
                                                int* __restrict__ aux) {
    __shared__ int wtot[16];
    int t = threadIdx.x;
    int i = blockIdx.x * 1024 + t;
    int lane = t & 63, wave = t >> 6;
    int v = (i < NN) ? deg[i] + 1 : 0;
    int inc = v;
    #pragma unroll
    for (int off = 1; off < 64; off <<= 1) {
        int u = __shfl_up(inc, off, 64);
        if (lane >= off) inc += u;
    }
    if (lane == 63) wtot[wave] = inc;
    __syncthreads();
    if (wave == 0 && lane < 16) {
        int w = wtot[lane];
        int iw = w;
        #pragma unroll
        for (int off = 1; off < 16; off <<= 1) {
            int u = __shfl_up(iw, off, 64);
            if (lane >= off) iw += u;
        }
        wtot[lane] = iw - w;   // exclusive
    }
    __syncthreads();
    int excl = inc - v + wtot[wave];
    if (i < NN) row_ptr[i] = excl;
    if (t == 1023) aux[blockIdx.x] = excl + v;   // block total
}

// scan3 with self-computed aux prefix (drops the separate scan2 kernel)
__global__ void k_scan3(int* __restrict__ row_ptr, const int* __restrict__ aux,
                        int* __restrict__ wp) {
    __shared__ int sAux[NSCAN];
    int t = threadIdx.x;
    if (t < 64) {
        int v = (t < NSCAN) ? aux[t] : 0;
        int inc = v;
        #pragma unroll
        for (int off = 1; off < 64; off <<= 1) {
            int u = __shfl_up(inc, off, 64);
            if (t >= off) inc += u;
        }
        if (t < NSCAN) sAux[t] = inc - v;   // exclusive
    }
    __syncthreads();
    int i = blockIdx.x * 256 + t;
    if (i < NN) {
        int v = row_ptr[i] + sAux[i >> 10];
        row_ptr[i] = v;
        wp[i] = v;
    }
    if (i == 0) row_ptr[NN] = EP;
}

__global__ void k_scatter(const int* __restrict__ ei, int* __restrict__ wp,
                          int* __restrict__ esrc) {
    int i = blockIdx.x * 256 + threadIdx.x;
    if (i < EE) {
        int s = ei[i];
        int d = ei[EE + i];
        int pos = atomicAdd(&wp[d], 1);
        esrc[pos] = s;
    } else if (i < EP) {
        int n = i - EE;
        int pos = atomicAdd(&wp[n], 1);
        esrc[pos] = n;   // self loop
    }
}

// ---------------------------------------------------------------------------
// prep: gemm1 A-fragment image (17 tiles; tile 16 = va computed inline)
// + W2 bf16 cast. One kernel.
// ---------------------------------------------------------------------------
__global__ void k_prepfw(const float* __restrict__ W1, const float* __restrict__ a1s,
                         const float* __restrict__ a1d, const float* __restrict__ W2,
                         unsigned short* __restrict__ w1frag,
                         unsigned short* __restrict__ W2b) {
    int i = blockIdx.x * 256 + threadIdx.x;
    if (i < 17 * 2048) {
        int j = i & 7, lane = (i >> 3) & 63, s = (i >> 9) & 3, c = i >> 11;
        int q = lane >> 4, m = lane & 15;
        int k = s * 32 + q * 8 + j;
        float val;
        if (c < 16) {
            val = W1[k * C1 + c * 16 + m];
        } else {
            int h = m & 7;
            const float* av = (m < 8) ? a1s : a1d;
            float acc = 0.f;
            #pragma unroll
            for (int j2 = 0; j2 < 32; j2++)
                acc += W1[k * C1 + h * 32 + j2] * av[h * 32 + j2];
            val = acc;
        }
        w1frag[i] = f2bf(val);
    } else if (i < 17 * 2048 + C1 * DOUT) {
        int j = i - 17 * 2048;
        W2b[j] = f2bf(W2[j]);
    }
}

// ---------------------------------------------------------------------------
// GEMM1 via MFMA (operand-swapped). Node-major h1b[node][256] epilogue +
// al1sd fp32 [node][16] (0-7 src, 8-15 dst) + packed bf16 al1s8[node][8]
// (src logits only -- agg1 phase-1 reads 16 B instead of 32 B per edge).
// ---------------------------------------------------------------------------
__global__ __launch_bounds__(256) void k_gemm1(const float* __restrict__ x,
                                               const unsigned short* __restrict__ w1frag,
                                               unsigned short* __restrict__ h1b,
                                               float* __restrict__ al1sd,
                                               unsigned short* __restrict__ al1s8) {
    int wid = (blockIdx.x * 256 + threadIdx.x) >> 6;
    int lane = threadIdx.x & 63;
    if (wid >= NW1) return;
    int nb = wid * 16;
    int m = lane & 15, quad = lane >> 4;
    const float* xrow = x + (nb + m) * DIN;

    float4 xf[8];
    #pragma unroll
    for (int s = 0; s < 4; s++) {
        xf[2 * s]     = *(const float4*)(xrow + s * 32 + quad * 8);
        xf[2 * s + 1] = *(const float4*)(xrow + s * 32 + quad * 8 + 4);
    }
    short8 bfr[4];
    #pragma unroll
    for (int s = 0; s < 4; s++) {
        unsigned short* bp = (unsigned short*)&bfr[s];
        float4 f0 = xf[2 * s], f1 = xf[2 * s + 1];
        bp[0] = f2bf(f0.x); bp[1] = f2bf(f0.y); bp[2] = f2bf(f0.z); bp[3] = f2bf(f0.w);
        bp[4] = f2bf(f1.x); bp[5] = f2bf(f1.y); bp[6] = f2bf(f1.z); bp[7] = f2bf(f1.w);
    }

    float4v acc[17];
    #pragma unroll
    for (int c = 0; c < 17; c++) acc[c] = (float4v){0.f, 0.f, 0.f, 0.f};

    #pragma unroll
    for (int s = 0; s < 4; s++) {
        const unsigned short* fp = w1frag + (s * 64 + lane) * 8;
        #pragma unroll
        for (int c = 0; c < 17; c++) {
            short8 afrag = *(const short8*)(fp + c * 2048);
            acc[c] = __builtin_amdgcn_mfma_f32_16x16x32_bf16(afrag, bfr[s], acc[c], 0, 0, 0);
        }
    }

    int node = nb + m;
    #pragma unroll
    for (int c = 0; c < 16; c++) {
        uint2 pk;
        pk.x = (unsigned)f2bf(acc[c][0]) | ((unsigned)f2bf(acc[c][1]) << 16);
        pk.y = (unsigned)f2bf(acc[c][2]) | ((unsigned)f2bf(acc[c][3]) << 16);
        *(uint2*)(h1b + node * C1 + c * 16 + quad * 4) = pk;
    }
    *(float4*)(al1sd + node * 16 + quad * 4) =
        make_float4(acc[16][0], acc[16][1], acc[16][2], acc[16][3]);
    if (quad < 2) {   // src logits (rows 0-7) packed bf16
        uint2 pk;
        pk.x = (unsigned)f2bf(acc[16][0]) | ((unsigned)f2bf(acc[16][1]) << 16);
        pk.y = (unsigned)f2bf(acc[16][2]) | ((unsigned)f2bf(acc[16][3]) << 16);
        *(uint2*)(al1s8 + node * 8 + quad * 4) = pk;
    }
}

// ---------------------------------------------------------------------------
// agg1 (R5 winner structure): one wave per dst node, two-phase, node range
// [n0, n0+25000). Phase 1: lane e computes all 8 head-weights of edge e
// (al1s8 bf16 row = one 16 B load). Phase 2: 4 edges in flight, 512 B/edge.
// ---------------------------------------------------------------------------
__global__ __launch_bounds__(256) void k_agg1(const int* __restrict__ row_ptr,
                                              const int* __restrict__ esrc,
                                              const unsigned short* __restrict__ h1b,
                                              const unsigned short* __restrict__ al1s8,
                                              const float* __restrict__ al1sd,
                                              const float* __restrict__ b1,
                                              unsigned short* __restrict__ helu_b,
                                              int n0) {
    __shared__ float wbuf[4][64 * 8];
    __shared__ int   sbuf[4][64];
    int wslot = threadIdx.x >> 6;
    int L = threadIdx.x & 63;
    int d = n0 + ((blockIdx.x * 256 + threadIdx.x) >> 6);
    int h = L >> 3;
    int start = row_ptr[d], end = row_ptr[d + 1];
    float4 ald0 = *(const float4*)(al1sd + d * 16 + 8);
    float4 ald1 = *(const float4*)(al1sd + d * 16 + 12);
    float* wrow = wbuf[wslot];
    int* srow = sbuf[wslot];
    float denom = 0.f;
    float4 acc = make_float4(0.f, 0.f, 0.f, 0.f);
    const int Lofs = L * 4;

    for (int base = start; base < end; base += 64) {
        int cnt = min(64, end - base);
        // phase 1: lane e -> 8 head-weights of edge e
        int s = d;
        float wv0 = 0.f, wv1 = 0.f, wv2 = 0.f, wv3 = 0.f;
        float wv4 = 0.f, wv5 = 0.f, wv6 = 0.f, wv7 = 0.f;
        if (L < cnt) {
            s = esrc[base + L];
            uint4 as = *(const uint4*)(al1s8 + s * 8);
            float e;
            e = bflo(as.x) + ald0.x; e = e > 0.f ? e : 0.2f * e; wv0 = __expf(e);
            e = bfhi(as.x) + ald0.y; e = e > 0.f ? e : 0.2f * e; wv1 = __expf(e);
            e = bflo(as.y) + ald0.z; e = e > 0.f ? e : 0.2f * e; wv2 = __expf(e);
            e = bfhi(as.y) + ald0.w; e = e > 0.f ? e : 0.2f * e; wv3 = __expf(e);
            e = bflo(as.z) + ald1.x; e = e > 0.f ? e : 0.2f * e; wv4 = __expf(e);
            e = bfhi(as.z) + ald1.y; e = e > 0.f ? e : 0.2f * e; wv5 = __expf(e);
            e = bflo(as.w) + ald1.z; e = e > 0.f ? e : 0.2f * e; wv6 = __expf(e);
            e = bfhi(as.w) + ald1.w; e = e > 0.f ? e : 0.2f * e; wv7 = __expf(e);
        }
        srow[L] = s;
        *(float4*)&wrow[L * 8]     = make_float4(wv0, wv1, wv2, wv3);
        *(float4*)&wrow[L * 8 + 4] = make_float4(wv4, wv5, wv6, wv7);
        // phase 2: 4 edges/iter, 512 B/edge (uint2 x 64 lanes)
        int cnt4 = (cnt + 3) & ~3;
        for (int i = 0; i < cnt4; i += 4) {
            int s0 = srow[i], s1 = srow[i + 1], s2 = srow[i + 2], s3 = srow[i + 3];
            float x0 = wrow[i * 8 + h];
            float x1 = wrow[i * 8 + 8 + h];
            float x2 = wrow[i * 8 + 16 + h];
            float x3 = wrow[i * 8 + 24 + h];
            uint2 v0 = *(const uint2*)(h1b + s0 * C1 + Lofs);
            uint2 v1 = *(const uint2*)(h1b + s1 * C1 + Lofs);
            uint2 v2 = *(const uint2*)(h1b + s2 * C1 + Lofs);
            uint2 v3 = *(const uint2*)(h1b + s3 * C1 + Lofs);
            denom += (x0 + x1) + (x2 + x3);
            acc.x += x0 * bflo(v0.x); acc.y += x0 * bfhi(v0.x);
            acc.z += x0 * bflo(v0.y); acc.w += x0 * bfhi(v0.y);
            acc.x += x1 * bflo(v1.x); acc.y += x1 * bfhi(v1.x);
            acc.z += x1 * bflo(v1.y); acc.w += x1 * bfhi(v1.y);
            acc.x += x2 * bflo(v2.x); acc.y += x2 * bfhi(v2.x);
            acc.z += x2 * bflo(v2.y); acc.w += x2 * bfhi(v2.y);
            acc.x += x3 * bflo(v3.x); acc.y += x3 * bfhi(v3.x);
            acc.z += x3 * bflo(v3.y); acc.w += x3 * bfhi(v3.y);
        }
    }
    float inv = 1.0f / (denom + 1e-16f);
    float4 bv = *(const float4*)(b1 + Lofs);
    float o0 = acc.x * inv + bv.x;
    float o1 = acc.y * inv + bv.y;
    float o2 = acc.z * inv + bv.z;
    float o3 = acc.w * inv + bv.w;
    o0 = o0 > 0.f ? o0 : __expf(o0) - 1.0f;
    o1 = o1 > 0.f ? o1 : __expf(o1) - 1.0f;
    o2 = o2 > 0.f ? o2 : __expf(o2) - 1.0f;
    o3 = o3 > 0.f ? o3 : __expf(o3) - 1.0f;
    uint2 pk;
    pk.x = (unsigned)f2bf(o0) | ((unsigned)f2bf(o1) << 16);
    pk.y = (unsigned)f2bf(o2) | ((unsigned)f2bf(o3) << 16);
    *(uint2*)(helu_b + d * C1 + Lofs) = pk;
}

// ---------------------------------------------------------------------------
// GEMM2 via MFMA 16x16x32 bf16 + fused al2 epilogue (unchanged).
// ---------------------------------------------------------------------------
__global__ __launch_bounds__(256) void k_gemm2(const unsigned short* __restrict__ helu_b,
                                               const unsigned short* __restrict__ W2b,
                                               const float* __restrict__ a2s,
                                               const float* __restrict__ a2d,
                                               unsigned short* __restrict__ h2b,
                                               float* __restrict__ al2s,
                                               float* __restrict__ al2d) {
    int wid = (blockIdx.x * 256 + threadIdx.x) >> 6;
    int lane = threadIdx.x & 63;
    int nb = wid * 16;
    if (nb >= NN) return;
    int m = lane & 15, quad = lane >> 4;

    short8 bfrag[8];
    #pragma unroll
    for (int s = 0; s < 8; s++) {
        #pragma unroll
        for (int j = 0; j < 8; j++) {
            ((short*)&bfrag[s])[j] = (short)W2b[(s * 32 + quad * 8 + j) * DOUT + m];
        }
    }

    float4v acc = {0.f, 0.f, 0.f, 0.f};
    const unsigned short* arow = helu_b + (nb + m) * C1 + quad * 8;
    #pragma unroll
    for (int s = 0; s < 8; s++) {
        short8 afrag = *(const short8*)(arow + s * 32);
        acc = __builtin_amdgcn_mfma_f32_16x16x32_bf16(afrag, bfrag[s], acc, 0, 0, 0);
    }

    float as_c = a2s[m], ad_c = a2d[m];
    #pragma unroll
    for (int r = 0; r < 4; r++) {
        int node = nb + quad * 4 + r;
        float val = acc[r];
        h2b[node * DOUT + m] = f2bf(val);
        float ps = val * as_c;
        float pd = val * ad_c;
        ps += __shfl_xor(ps, 1, 64); ps += __shfl_xor(ps, 2, 64);
        ps += __shfl_xor(ps, 4, 64); ps += __shfl_xor(ps, 8, 64);
        pd += __shfl_xor(pd, 1, 64); pd += __shfl_xor(pd, 2, 64);
        pd += __shfl_xor(pd, 4, 64); pd += __shfl_xor(pd, 8, 64);
        if (m == 0) {
            al2s[node] = ps;
            al2d[node] = pd;
        }
    }
}

// ---------------------------------------------------------------------------
// agg2 + bias + log_softmax (unchanged two-phase).
// ---------------------------------------------------------------------------
__global__ __launch_bounds__(256) void k_agg2(const int* __restrict__ row_ptr,
                                              const int* __restrict__ esrc,
                                              const unsigned short* __restrict__ h2b,
                                              const float* __restrict__ al2s,
                                              const float* __restrict__ al2d,
                                              const float* __restrict__ b2,
                                              float* __restrict__ out) {
    __shared__ float wbuf2[4][64];
    __shared__ int   sbuf2[4][64];
    int wslot = threadIdx.x >> 6;
    int L = threadIdx.x & 63;
    int n = (blockIdx.x * 256 + threadIdx.x) >> 6;
    if (n >= NN) return;
    int c = L & 15, g = L >> 4;
    int start = row_ptr[n], end = row_ptr[n + 1];
    float ald = al2d[n];
    float* wrow = wbuf2[wslot];
    int* srow = sbuf2[wslot];
    float acc = 0.f, denom = 0.f;

    for (int base = start; base < end; base += 64) {
        int cnt = min(64, end - base);
        int s = n; float w = 0.f;
        if (L < cnt) {
            s = esrc[base + L];
            float e = al2s[s] + ald;
            e = e > 0.f ? e : 0.2f * e;
            w = __expf(e);
        }
        srow[L] = s;
        wrow[L] = w;
        int cnt4 = (cnt + 3) & ~3;
        for (int i = 0; i < cnt4; i += 4) {
            int idx = i + g;
            int ss = srow[idx];
            float ww = wrow[idx];
            float v = bf2f(h2b[ss * DOUT + c]);
            acc += ww * v;
            denom += ww;
        }
    }
    acc += __shfl_xor(acc, 16, 64);   acc += __shfl_xor(acc, 32, 64);
    denom += __shfl_xor(denom, 16, 64); denom += __shfl_xor(denom, 32, 64);
    float val = acc / (denom + 1e-16f) + b2[c];
    float m = val;
    #pragma unroll
    for (int mm = 1; mm < 16; mm <<= 1) m = fmaxf(m, __shfl_xor(m, mm, 64));
    float ex = __expf(val - m);
    float se = ex;
    #pragma unroll
    for (int mm = 1; mm < 16; mm <<= 1) se += __shfl_xor(se, mm, 64);
    if (L < 16) out[n * DOUT + c] = val - m - __logf(se);
}

// ---------------------------------------------------------------------------
extern "C" void kernel_launch(void* const* d_in, const int* in_sizes, int n_in,
                              void* d_out, int out_size, void* d_ws, size_t ws_size,
                              hipStream_t stream) {
    const float* x   = (const float*)d_in[0];
    const int*   ei  = (const int*)d_in[1];
    const float* W1  = (const float*)d_in[2];
    const float* a1s = (const float*)d_in[3];
    const float* a1d = (const float*)d_in[4];
    const float* b1  = (const float*)d_in[5];
    const float* W2  = (const float*)d_in[6];
    const float* a2s = (const float*)d_in[7];
    const float* a2d = (const float*)d_in[8];
    const float* b2  = (const float*)d_in[9];
    float* outp = (float*)d_out;

    // workspace layout
    unsigned short* h1b    = (unsigned short*)d_ws;      // N*256 bf16 node-major
    unsigned short* helu_b = h1b + NN * C1;              // N*256 bf16
    unsigned short* h2b    = helu_b + NN * C1;           // N*16 bf16
    unsigned short* W2b    = h2b + NN * DOUT;            // 4096 bf16
    unsigned short* w1frag = W2b + C1 * DOUT;            // 34816 bf16
    unsigned short* al1s8  = w1frag + 17 * 2048;         // N*8 bf16 (src logits)
    float* al1sd = (float*)(al1s8 + NN * 8);             // N*16 fp32
    float* al2sb = al1sd + NN * 16;                      // N
    float* al2db = al2sb + NN;                           // N
    int* deg     = (int*)(al2db + NN);                   // N
    int* row_ptr = deg + NN;                             // N+1
    int* wp      = row_ptr + NN + 1;                     // N
    int* esrc    = wp + NN;                              // EP
    int* aux     = esrc + EP;                            // 64

    hipMemsetAsync(deg, 0, NN * sizeof(int), stream);
    k_countdeg<<<(EE + 255) / 256, 256, 0, stream>>>(ei, deg);
    k_scan1<<<NSCAN, 1024, 0, stream>>>(deg, row_ptr, aux);
    k_scan3<<<(NN + 255) / 256, 256, 0, stream>>>(row_ptr, aux, wp);
    k_scatter<<<(EP + 255) / 256, 256, 0, stream>>>(ei, wp, esrc);

    k_prepfw<<<(17 * 2048 + C1 * DOUT + 255) / 256, 256, 0, stream>>>(W1, a1s, a1d, W2, w1frag, W2b);
    k_gemm1<<<(NW1 * 64 + 255) / 256, 256, 0, stream>>>(x, w1frag, h1b, al1sd, al1s8);
    // two node-range halves (also exposes the #2 kernel in the profile)
    k_agg1<<<25000 / 4, 256, 0, stream>>>(row_ptr, esrc, h1b, al1s8, al1sd, b1, helu_b, 0);
    k_agg1<<<25000 / 4, 256, 0, stream>>>(row_ptr, esrc, h1b, al1s8, al1sd, b1, helu_b, 25000);

    k_gemm2<<<(NW1 * 64 + 255) / 256, 256, 0, stream>>>(helu_b, W2b, a2s, a2d, h2b, al2sb, al2db);
    k_agg2<<<(NN * 64 + 255) / 256, 256, 0, stream>>>(row_ptr, esrc, h2b, al2sb, al2db, b2, outp);
}

// Round 9
// 290.635 us; speedup vs baseline: 1.4595x; 1.0127x over previous
//
#include <hip/hip_runtime.h>
#include <hip/hip_bf16.h>

// Problem constants (match reference)
#define NN 50000
#define EE 800000
#define EP (EE + NN)        // edges + self loops = 850000
#define DIN 128
#define HID 32
#define HEADS 8
#define C1 (HEADS * HID)    // 256
#define DOUT 16
#define NW1 3125            // gemm1/gemm2 waves: 50000/16
#define NSCAN 49            // ceil(50000/1024)
#define KB 49               // dst buckets (1024 nodes each)
#define EPT 8               // edges per thread in k_bucket
#define BBLK (256 * EPT)    // 2048 edges per block

typedef __attribute__((ext_vector_type(8))) short short8;   // 8 bf16 (4 VGPRs)
typedef __attribute__((ext_vector_type(4))) float float4v;  // MFMA C/D

__device__ inline unsigned short f2bf(float f) {
    __hip_bfloat16 b = __float2bfloat16(f);
    return *reinterpret_cast<unsigned short*>(&b);
}
__device__ inline float bf2f(unsigned short u) {
    union { unsigned int i; float f; } x;
    x.i = ((unsigned int)u) << 16;
    return x.f;
}
__device__ inline float bflo(unsigned u) {
    union { unsigned int i; float f; } x;
    x.i = u << 16;
    return x.f;
}
__device__ inline float bfhi(unsigned u) {
    union { unsigned int i; float f; } x;
    x.i = u & 0xffff0000u;
    return x.f;
}

// ---------------------------------------------------------------------------
// CSR build (deg zeroed via hipMemsetAsync; self loop folded as +1 in scan1)
// ---------------------------------------------------------------------------
__global__ void k_countdeg(const int* __restrict__ ei, int* __restrict__ deg) {
    int i = blockIdx.x * 256 + threadIdx.x;
    if (i < EE) atomicAdd(&deg[ei[EE + i]], 1);
}

// shfl-based block scan (1024 thr = 16 waves); v = deg[i]+1 (self loop)
__global__ __launch_bounds__(1024) void k_scan1(const int* __restrict__ deg,
                                                int* __restrict__ row_ptr,
                                                int* __restrict__ aux) {
    __shared__ int wtot[16];
    int t = threadIdx.x;
    int i = blockIdx.x * 1024 + t;
    int lane = t & 63, wave = t >> 6;
    int v = (i < NN) ? deg[i] + 1 : 0;
    int inc = v;
    #pragma unroll
    for (int off = 1; off < 64; off <<= 1) {
        int u = __shfl_up(inc, off, 64);
        if (lane >= off) inc += u;
    }
    if (lane == 63) wtot[wave] = inc;
    __syncthreads();
    if (wave == 0 && lane < 16) {
        int w = wtot[lane];
        int iw = w;
        #pragma unroll
        for (int off = 1; off < 16; off <<= 1) {
            int u = __shfl_up(iw, off, 64);
            if (lane >= off) iw += u;
        }
        wtot[lane] = iw - w;   // exclusive
    }
    __syncthreads();
    int excl = inc - v + wtot[wave];
    if (i < NN) row_ptr[i] = excl;
    if (t == 1023) aux[blockIdx.x] = excl + v;   // block total
}

// scan3: finalize row_ptr, init wp, init per-bucket write pointers wpb
__global__ void k_scan3(int* __restrict__ row_ptr, const int* __restrict__ aux,
                        int* __restrict__ wp, int* __restrict__ wpb) {
    __shared__ int sAux[NSCAN];
    int t = threadIdx.x;
    if (t < 64) {
        int v = (t < NSCAN) ? aux[t] : 0;
        int inc = v;
        #pragma unroll
        for (int off = 1; off < 64; off <<= 1) {
            int u = __shfl_up(inc, off, 64);
            if (t >= off) inc += u;
        }
        if (t < NSCAN) sAux[t] = inc - v;   // exclusive
    }
    __syncthreads();
    int i = blockIdx.x * 256 + t;
    if (i < NN) {
        int v = row_ptr[i] + sAux[i >> 10];
        row_ptr[i] = v;
        wp[i] = v;
        if ((i & 1023) == 0) wpb[i >> 10] = v;   // bucket base = CSR offset
    }
    if (i == 0) row_ptr[NN] = EP;
}

// ---------------------------------------------------------------------------
// pass 2: bucket edges by dst>>10 into ebuf (bucket-grouped (src,dst) pairs).
// One global atomic per (block,bucket); per-edge rank via LDS atomics.
// Writes land in ~40-entry contiguous runs -> good HBM write efficiency.
// ---------------------------------------------------------------------------
__global__ __launch_bounds__(256) void k_bucket(const int* __restrict__ ei,
                                                int* __restrict__ wpb,
                                                int2* __restrict__ ebuf) {
    __shared__ int hist[KB];
    __shared__ int base[KB];
    int t = threadIdx.x;
    if (t < KB) hist[t] = 0;
    __syncthreads();
    int e0 = blockIdx.x * BBLK;
    int s[EPT], d[EPT], r[EPT];
    #pragma unroll
    for (int j = 0; j < EPT; j++) {
        int e = e0 + j * 256 + t;
        int ss = 0, dd = -1;
        if (e < EE) { ss = ei[e]; dd = ei[EE + e]; }
        else if (e < EP) { ss = e - EE; dd = ss; }   // self loop
        s[j] = ss; d[j] = dd;
        if (dd >= 0) r[j] = atomicAdd(&hist[dd >> 10], 1);
    }
    __syncthreads();
    if (t < KB) base[t] = hist[t] ? atomicAdd(&wpb[t], hist[t]) : 0;
    __syncthreads();
    #pragma unroll
    for (int j = 0; j < EPT; j++) {
        if (d[j] >= 0) ebuf[base[d[j] >> 10] + r[j]] = make_int2(s[j], d[j]);
    }
}

// ---------------------------------------------------------------------------
// pass 3: final CSR scatter from bucket-grouped ebuf. Each dst's positions
// live in a ~70 KB L2-resident window -> write lines fill before eviction.
// ---------------------------------------------------------------------------
__global__ void k_scatter2(const int2* __restrict__ ebuf, int* __restrict__ wp,
                           int* __restrict__ esrc) {
    int i = blockIdx.x * 256 + threadIdx.x;
    if (i < EP) {
        int2 e = ebuf[i];
        int pos = atomicAdd(&wp[e.y], 1);
        esrc[pos] = e.x;
    }
}

// ---------------------------------------------------------------------------
// prep: gemm1 A-fragment image (17 tiles; tile 16 = va computed inline)
// + W2 bf16 cast. One kernel.
// ---------------------------------------------------------------------------
__global__ void k_prepfw(const float* __restrict__ W1, const float* __restrict__ a1s,
                         const float* __restrict__ a1d, const float* __restrict__ W2,
                         unsigned short* __restrict__ w1frag,
                         unsigned short* __restrict__ W2b) {
    int i = blockIdx.x * 256 + threadIdx.x;
    if (i < 17 * 2048) {
        int j = i & 7, lane = (i >> 3) & 63, s = (i >> 9) & 3, c = i >> 11;
        int q = lane >> 4, m = lane & 15;
        int k = s * 32 + q * 8 + j;
        float val;
        if (c < 16) {
            val = W1[k * C1 + c * 16 + m];
        } else {
            int h = m & 7;
            const float* av = (m < 8) ? a1s : a1d;
            float acc = 0.f;
            #pragma unroll
            for (int j2 = 0; j2 < 32; j2++)
                acc += W1[k * C1 + h * 32 + j2] * av[h * 32 + j2];
            val = acc;
        }
        w1frag[i] = f2bf(val);
    } else if (i < 17 * 2048 + C1 * DOUT) {
        int j = i - 17 * 2048;
        W2b[j] = f2bf(W2[j]);
    }
}

// ---------------------------------------------------------------------------
// GEMM1 via MFMA (operand-swapped). Node-major h1b[node][256] epilogue +
// al1sd fp32 [node][16] (0-7 src, 8-15 dst) + packed bf16 al1s8[node][8].
// ---------------------------------------------------------------------------
__global__ __launch_bounds__(256) void k_gemm1(const float* __restrict__ x,
                                               const unsigned short* __restrict__ w1frag,
                                               unsigned short* __restrict__ h1b,
                                               float* __restrict__ al1sd,
                                               unsigned short* __restrict__ al1s8) {
    int wid = (blockIdx.x * 256 + threadIdx.x) >> 6;
    int lane = threadIdx.x & 63;
    if (wid >= NW1) return;
    int nb = wid * 16;
    int m = lane & 15, quad = lane >> 4;
    const float* xrow = x + (nb + m) * DIN;

    float4 xf[8];
    #pragma unroll
    for (int s = 0; s < 4; s++) {
        xf[2 * s]     = *(const float4*)(xrow + s * 32 + quad * 8);
        xf[2 * s + 1] = *(const float4*)(xrow + s * 32 + quad * 8 + 4);
    }
    short8 bfr[4];
    #pragma unroll
    for (int s = 0; s < 4; s++) {
        unsigned short* bp = (unsigned short*)&bfr[s];
        float4 f0 = xf[2 * s], f1 = xf[2 * s + 1];
        bp[0] = f2bf(f0.x); bp[1] = f2bf(f0.y); bp[2] = f2bf(f0.z); bp[3] = f2bf(f0.w);
        bp[4] = f2bf(f1.x); bp[5] = f2bf(f1.y); bp[6] = f2bf(f1.z); bp[7] = f2bf(f1.w);
    }

    float4v acc[17];
    #pragma unroll
    for (int c = 0; c < 17; c++) acc[c] = (float4v){0.f, 0.f, 0.f, 0.f};

    #pragma unroll
    for (int s = 0; s < 4; s++) {
        const unsigned short* fp = w1frag + (s * 64 + lane) * 8;
        #pragma unroll
        for (int c = 0; c < 17; c++) {
            short8 afrag = *(const short8*)(fp + c * 2048);
            acc[c] = __builtin_amdgcn_mfma_f32_16x16x32_bf16(afrag, bfr[s], acc[c], 0, 0, 0);
        }
    }

    int node = nb + m;
    #pragma unroll
    for (int c = 0; c < 16; c++) {
        uint2 pk;
        pk.x = (unsigned)f2bf(acc[c][0]) | ((unsigned)f2bf(acc[c][1]) << 16);
        pk.y = (unsigned)f2bf(acc[c][2]) | ((unsigned)f2bf(acc[c][3]) << 16);
        *(uint2*)(h1b + node * C1 + c * 16 + quad * 4) = pk;
    }
    *(float4*)(al1sd + node * 16 + quad * 4) =
        make_float4(acc[16][0], acc[16][1], acc[16][2], acc[16][3]);
    if (quad < 2) {   // src logits (rows 0-7) packed bf16
        uint2 pk;
        pk.x = (unsigned)f2bf(acc[16][0]) | ((unsigned)f2bf(acc[16][1]) << 16);
        pk.y = (unsigned)f2bf(acc[16][2]) | ((unsigned)f2bf(acc[16][3]) << 16);
        *(uint2*)(al1s8 + node * 8 + quad * 4) = pk;
    }
}

// ---------------------------------------------------------------------------
// agg1 (R5 winner structure): one wave per dst node, two-phase, node range
// [n0, n0+25000).
// ---------------------------------------------------------------------------
__global__ __launch_bounds__(256) void k_agg1(const int* __restrict__ row_ptr,
                                              const int* __restrict__ esrc,
                                              const unsigned short* __restrict__ h1b,
                                              const unsigned short* __restrict__ al1s8,
                                              const float* __restrict__ al1sd,
                                              const float* __restrict__ b1,
                                              unsigned short* __restrict__ helu_b,
                                              int n0) {
    __shared__ float wbuf[4][64 * 8];
    __shared__ int   sbuf[4][64];
    int wslot = threadIdx.x >> 6;
    int L = threadIdx.x & 63;
    int d = n0 + ((blockIdx.x * 256 + threadIdx.x) >> 6);
    int h = L >> 3;
    int start = row_ptr[d], end = row_ptr[d + 1];
    float4 ald0 = *(const float4*)(al1sd + d * 16 + 8);
    float4 ald1 = *(const float4*)(al1sd + d * 16 + 12);
    float* wrow = wbuf[wslot];
    int* srow = sbuf[wslot];
    float denom = 0.f;
    float4 acc = make_float4(0.f, 0.f, 0.f, 0.f);
    const int Lofs = L * 4;

    for (int base = start; base < end; base += 64) {
        int cnt = min(64, end - base);
        int s = d;
        float wv0 = 0.f, wv1 = 0.f, wv2 = 0.f, wv3 = 0.f;
        float wv4 = 0.f, wv5 = 0.f, wv6 = 0.f, wv7 = 0.f;
        if (L < cnt) {
            s = esrc[base + L];
            uint4 as = *(const uint4*)(al1s8 + s * 8);
            float e;
            e = bflo(as.x) + ald0.x; e = e > 0.f ? e : 0.2f * e; wv0 = __expf(e);
            e = bfhi(as.x) + ald0.y; e = e > 0.f ? e : 0.2f * e; wv1 = __expf(e);
            e = bflo(as.y) + ald0.z; e = e > 0.f ? e : 0.2f * e; wv2 = __expf(e);
            e = bfhi(as.y) + ald0.w; e = e > 0.f ? e : 0.2f * e; wv3 = __expf(e);
            e = bflo(as.z) + ald1.x; e = e > 0.f ? e : 0.2f * e; wv4 = __expf(e);
            e = bfhi(as.z) + ald1.y; e = e > 0.f ? e : 0.2f * e; wv5 = __expf(e);
            e = bflo(as.w) + ald1.z; e = e > 0.f ? e : 0.2f * e; wv6 = __expf(e);
            e = bfhi(as.w) + ald1.w; e = e > 0.f ? e : 0.2f * e; wv7 = __expf(e);
        }
        srow[L] = s;
        *(float4*)&wrow[L * 8]     = make_float4(wv0, wv1, wv2, wv3);
        *(float4*)&wrow[L * 8 + 4] = make_float4(wv4, wv5, wv6, wv7);
        int cnt4 = (cnt + 3) & ~3;
        for (int i = 0; i < cnt4; i += 4) {
            int s0 = srow[i], s1 = srow[i + 1], s2 = srow[i + 2], s3 = srow[i + 3];
            float x0 = wrow[i * 8 + h];
            float x1 = wrow[i * 8 + 8 + h];
            float x2 = wrow[i * 8 + 16 + h];
            float x3 = wrow[i * 8 + 24 + h];
            uint2 v0 = *(const uint2*)(h1b + s0 * C1 + Lofs);
            uint2 v1 = *(const uint2*)(h1b + s1 * C1 + Lofs);
            uint2 v2 = *(const uint2*)(h1b + s2 * C1 + Lofs);
            uint2 v3 = *(const uint2*)(h1b + s3 * C1 + Lofs);
            denom += (x0 + x1) + (x2 + x3);
            acc.x += x0 * bflo(v0.x); acc.y += x0 * bfhi(v0.x);
            acc.z += x0 * bflo(v0.y); acc.w += x0 * bfhi(v0.y);
            acc.x += x1 * bflo(v1.x); acc.y += x1 * bfhi(v1.x);
            acc.z += x1 * bflo(v1.y); acc.w += x1 * bfhi(v1.y);
            acc.x += x2 * bflo(v2.x); acc.y += x2 * bfhi(v2.x);
            acc.z += x2 * bflo(v2.y); acc.w += x2 * bfhi(v2.y);
            acc.x += x3 * bflo(v3.x); acc.y += x3 * bfhi(v3.x);
            acc.z += x3 * bflo(v3.y); acc.w += x3 * bfhi(v3.y);
        }
    }
    float inv = 1.0f / (denom + 1e-16f);
    float4 bv = *(const float4*)(b1 + Lofs);
    float o0 = acc.x * inv + bv.x;
    float o1 = acc.y * inv + bv.y;
    float o2 = acc.z * inv + bv.z;
    float o3 = acc.w * inv + bv.w;
    o0 = o0 > 0.f ? o0 : __expf(o0) - 1.0f;
    o1 = o1 > 0.f ? o1 : __expf(o1) - 1.0f;
    o2 = o2 > 0.f ? o2 : __expf(o2) - 1.0f;
    o3 = o3 > 0.f ? o3 : __expf(o3) - 1.0f;
    uint2 pk;
    pk.x = (unsigned)f2bf(o0) | ((unsigned)f2bf(o1) << 16);
    pk.y = (unsigned)f2bf(o2) | ((unsigned)f2bf(o3) << 16);
    *(uint2*)(helu_b + d * C1 + Lofs) = pk;
}

// ---------------------------------------------------------------------------
// GEMM2 via MFMA 16x16x32 bf16 + fused al2 epilogue (unchanged).
// ---------------------------------------------------------------------------
__global__ __launch_bounds__(256) void k_gemm2(const unsigned short* __restrict__ helu_b,
                                               const unsigned short* __restrict__ W2b,
                                               const float* __restrict__ a2s,
                                               const float* __restrict__ a2d,
                                               unsigned short* __restrict__ h2b,
                                               float* __restrict__ al2s,
                                               float* __restrict__ al2d) {
    int wid = (blockIdx.x * 256 + threadIdx.x) >> 6;
    int lane = threadIdx.x & 63;
    int nb = wid * 16;
    if (nb >= NN) return;
    int m = lane & 15, quad = lane >> 4;

    short8 bfrag[8];
    #pragma unroll
    for (int s = 0; s < 8; s++) {
        #pragma unroll
        for (int j = 0; j < 8; j++) {
            ((short*)&bfrag[s])[j] = (short)W2b[(s * 32 + quad * 8 + j) * DOUT + m];
        }
    }

    float4v acc = {0.f, 0.f, 0.f, 0.f};
    const unsigned short* arow = helu_b + (nb + m) * C1 + quad * 8;
    #pragma unroll
    for (int s = 0; s < 8; s++) {
        short8 afrag = *(const short8*)(arow + s * 32);
        acc = __builtin_amdgcn_mfma_f32_16x16x32_bf16(afrag, bfrag[s], acc, 0, 0, 0);
    }

    float as_c = a2s[m], ad_c = a2d[m];
    #pragma unroll
    for (int r = 0; r < 4; r++) {
        int node = nb + quad * 4 + r;
        float val = acc[r];
        h2b[node * DOUT + m] = f2bf(val);
        float ps = val * as_c;
        float pd = val * ad_c;
        ps += __shfl_xor(ps, 1, 64); ps += __shfl_xor(ps, 2, 64);
        ps += __shfl_xor(ps, 4, 64); ps += __shfl_xor(ps, 8, 64);
        pd += __shfl_xor(pd, 1, 64); pd += __shfl_xor(pd, 2, 64);
        pd += __shfl_xor(pd, 4, 64); pd += __shfl_xor(pd, 8, 64);
        if (m == 0) {
            al2s[node] = ps;
            al2d[node] = pd;
        }
    }
}

// ---------------------------------------------------------------------------
// agg2 + bias + log_softmax (unchanged two-phase).
// ---------------------------------------------------------------------------
__global__ __launch_bounds__(256) void k_agg2(const int* __restrict__ row_ptr,
                                              const int* __restrict__ esrc,
                                              const unsigned short* __restrict__ h2b,
                                              const float* __restrict__ al2s,
                                              const float* __restrict__ al2d,
                                              const float* __restrict__ b2,
                                              float* __restrict__ out) {
    __shared__ float wbuf2[4][64];
    __shared__ int   sbuf2[4][64];
    int wslot = threadIdx.x >> 6;
    int L = threadIdx.x & 63;
    int n = (blockIdx.x * 256 + threadIdx.x) >> 6;
    if (n >= NN) return;
    int c = L & 15, g = L >> 4;
    int start = row_ptr[n], end = row_ptr[n + 1];
    float ald = al2d[n];
    float* wrow = wbuf2[wslot];
    int* srow = sbuf2[wslot];
    float acc = 0.f, denom = 0.f;

    for (int base = start; base < end; base += 64) {
        int cnt = min(64, end - base);
        int s = n; float w = 0.f;
        if (L < cnt) {
            s = esrc[base + L];
            float e = al2s[s] + ald;
            e = e > 0.f ? e : 0.2f * e;
            w = __expf(e);
        }
        srow[L] = s;
        wrow[L] = w;
        int cnt4 = (cnt + 3) & ~3;
        for (int i = 0; i < cnt4; i += 4) {
            int idx = i + g;
            int ss = srow[idx];
            float ww = wrow[idx];
            float v = bf2f(h2b[ss * DOUT + c]);
            acc += ww * v;
            denom += ww;
        }
    }
    acc += __shfl_xor(acc, 16, 64);   acc += __shfl_xor(acc, 32, 64);
    denom += __shfl_xor(denom, 16, 64); denom += __shfl_xor(denom, 32, 64);
    float val = acc / (denom + 1e-16f) + b2[c];
    float m = val;
    #pragma unroll
    for (int mm = 1; mm < 16; mm <<= 1) m = fmaxf(m, __shfl_xor(m, mm, 64));
    float ex = __expf(val - m);
    float se = ex;
    #pragma unroll
    for (int mm = 1; mm < 16; mm <<= 1) se += __shfl_xor(se, mm, 64);
    if (L < 16) out[n * DOUT + c] = val - m - __logf(se);
}

// ---------------------------------------------------------------------------
extern "C" void kernel_launch(void* const* d_in, const int* in_sizes, int n_in,
                              void* d_out, int out_size, void* d_ws, size_t ws_size,
                              hipStream_t stream) {
    const float* x   = (const float*)d_in[0];
    const int*   ei  = (const int*)d_in[1];
    const float* W1  = (const float*)d_in[2];
    const float* a1s = (const float*)d_in[3];
    const float* a1d = (const float*)d_in[4];
    const float* b1  = (const float*)d_in[5];
    const float* W2  = (const float*)d_in[6];
    const float* a2s = (const float*)d_in[7];
    const float* a2d = (const float*)d_in[8];
    const float* b2  = (const float*)d_in[9];
    float* outp = (float*)d_out;

    // workspace layout
    unsigned short* h1b    = (unsigned short*)d_ws;      // N*256 bf16 node-major
    unsigned short* helu_b = h1b + NN * C1;              // N*256 bf16
    unsigned short* h2b    = helu_b + NN * C1;           // N*16 bf16
    unsigned short* W2b    = h2b + NN * DOUT;            // 4096 bf16
    unsigned short* w1frag = W2b + C1 * DOUT;            // 34816 bf16
    unsigned short* al1s8  = w1frag + 17 * 2048;         // N*8 bf16 (src logits)
    float* al1sd = (float*)(al1s8 + NN * 8);             // N*16 fp32
    float* al2sb = al1sd + NN * 16;                      // N
    float* al2db = al2sb + NN;                           // N
    int* deg     = (int*)(al2db + NN);                   // N
    int* row_ptr = deg + NN;                             // N+1
    int* wp      = row_ptr + NN + 1;                     // N
    int* esrc    = wp + NN;                              // EP
    int* aux     = esrc + EP;                            // 64
    int* wpb     = aux + 64;                             // KB
    int2* ebuf   = (int2*)(wpb + 64);                    // EP int2

    hipMemsetAsync(deg, 0, NN * sizeof(int), stream);
    k_countdeg<<<(EE + 255) / 256, 256, 0, stream>>>(ei, deg);
    k_scan1<<<NSCAN, 1024, 0, stream>>>(deg, row_ptr, aux);
    k_scan3<<<(NN + 255) / 256, 256, 0, stream>>>(row_ptr, aux, wp, wpb);
    k_bucket<<<(EP + BBLK - 1) / BBLK, 256, 0, stream>>>(ei, wpb, ebuf);
    k_scatter2<<<(EP + 255) / 256, 256, 0, stream>>>(ebuf, wp, esrc);

    k_prepfw<<<(17 * 2048 + C1 * DOUT + 255) / 256, 256, 0, stream>>>(W1, a1s, a1d, W2, w1frag, W2b);
    k_gemm1<<<(NW1 * 64 + 255) / 256, 256, 0, stream>>>(x, w1frag, h1b, al1sd, al1s8);
    k_agg1<<<25000 / 4, 256, 0, stream>>>(row_ptr, esrc, h1b, al1s8, al1sd, b1, helu_b, 0);
    k_agg1<<<25000 / 4, 256, 0, stream>>>(row_ptr, esrc, h1b, al1s8, al1sd, b1, helu_b, 25000);

    k_gemm2<<<(NW1 * 64 + 255) / 256, 256, 0, stream>>>(helu_b, W2b, a2s, a2d, h2b, al2sb, al2db);
    k_agg2<<<(NN * 64 + 255) / 256, 256, 0, stream>>>(row_ptr, esrc, h2b, al2sb, al2db, b2, outp);
}

// Round 10
// 242.335 us; speedup vs baseline: 1.7504x; 1.1993x over previous
//
#include <hip/hip_runtime.h>
#include <hip/hip_bf16.h>

// Problem constants (match reference)
#define NN 50000
#define EE 800000
#define EP (EE + NN)        // edges + self loops = 850000
#define DIN 128
#define HID 32
#define HEADS 8
#define C1 (HEADS * HID)    // 256
#define DOUT 16
#define NW1 3125            // gemm1/gemm2 waves: 50000/16
#define SH 9                // bucket shift: 512 nodes/bucket
#define NB 98               // ceil(50000/512)
#define CAP 16384           // per-bucket ebuf capacity (mean 8704, sigma~90)
#define EPT 8               // edges per thread in k_bucketA
#define BBLK (256 * EPT)    // 2048 edges per block

typedef __attribute__((ext_vector_type(8))) short short8;   // 8 bf16 (4 VGPRs)
typedef __attribute__((ext_vector_type(4))) float float4v;  // MFMA C/D

__device__ inline unsigned short f2bf(float f) {
    __hip_bfloat16 b = __float2bfloat16(f);
    return *reinterpret_cast<unsigned short*>(&b);
}
__device__ inline float bf2f(unsigned short u) {
    union { unsigned int i; float f; } x;
    x.i = ((unsigned int)u) << 16;
    return x.f;
}
__device__ inline float bflo(unsigned u) {
    union { unsigned int i; float f; } x;
    x.i = u << 16;
    return x.f;
}
__device__ inline float bfhi(unsigned u) {
    union { unsigned int i; float f; } x;
    x.i = u & 0xffff0000u;
    return x.f;
}

// ---------------------------------------------------------------------------
// CSR pass 1: bucket edges by dst>>9 into per-bucket regions of ebuf.
// LDS histogram; ONE global atomic per (block,bucket); self-loops folded in.
// ---------------------------------------------------------------------------
__global__ __launch_bounds__(256) void k_bucketA(const int* __restrict__ ei,
                                                 int* __restrict__ cntb,
                                                 int2* __restrict__ ebuf) {
    __shared__ int hist[NB];
    __shared__ int base[NB];
    int t = threadIdx.x;
    if (t < NB) hist[t] = 0;
    __syncthreads();
    int e0 = blockIdx.x * BBLK;
    int s[EPT], d[EPT], r[EPT];
    #pragma unroll
    for (int j = 0; j < EPT; j++) {
        int e = e0 + j * 256 + t;
        int ss = 0, dd = -1;
        if (e < EE) { ss = ei[e]; dd = ei[EE + e]; }
        else if (e < EP) { ss = e - EE; dd = ss; }   // self loop
        s[j] = ss; d[j] = dd;
        if (dd >= 0) r[j] = atomicAdd(&hist[dd >> SH], 1);
    }
    __syncthreads();
    if (t < NB) base[t] = hist[t] ? atomicAdd(&cntb[t], hist[t]) : 0;
    __syncthreads();
    #pragma unroll
    for (int j = 0; j < EPT; j++) {
        if (d[j] >= 0) {
            int b = d[j] >> SH;
            ebuf[b * CAP + base[b] + r[j]] = make_int2(s[j], d[j]);
        }
    }
}

// ---------------------------------------------------------------------------
// CSR pass 2: one block per bucket. LDS degree count -> LDS scan ->
// row_ptr write -> LDS-atomic rank scatter into the bucket's exclusive
// ~35 KB esrc window (single CU => full L2 line fill). Zero global atomics.
// ---------------------------------------------------------------------------
__global__ __launch_bounds__(1024) void k_csr(const int* __restrict__ cntb,
                                              const int2* __restrict__ ebuf,
                                              int* __restrict__ row_ptr,
                                              int* __restrict__ esrc) {
    __shared__ int sdeg[512];
    __shared__ int wtot[8];
    __shared__ int bpart[2];
    int b = blockIdx.x;
    int t = threadIdx.x;
    int lane = t & 63, wave = t >> 6;
    int nodes0 = b << SH;
    if (t < 512) sdeg[t] = 0;
    if (t < 128) {   // baseS = sum cntb[0..b-1] (two-wave butterfly sum)
        int v = (t < b) ? cntb[t] : 0;
        #pragma unroll
        for (int off = 1; off < 64; off <<= 1) v += __shfl_xor(v, off, 64);
        if (lane == 0) bpart[wave] = v;
    }
    __syncthreads();
    int baseS = bpart[0] + bpart[1];
    int cnt = cntb[b];
    const int2* eb = ebuf + b * CAP;
    for (int i = t; i < cnt; i += 1024)
        atomicAdd(&sdeg[eb[i].y & 511], 1);
    __syncthreads();
    int v = (t < 512) ? sdeg[t] : 0;
    int inc = v;
    #pragma unroll
    for (int off = 1; off < 64; off <<= 1) {
        int u = __shfl_up(inc, off, 64);
        if (lane >= off) inc += u;
    }
    if (t < 512 && lane == 63) wtot[wave] = inc;
    __syncthreads();
    if (wave == 0 && lane < 8) {
        int w = wtot[lane];
        int iw = w;
        #pragma unroll
        for (int off = 1; off < 8; off <<= 1) {
            int u = __shfl_up(iw, off, 64);
            if (lane >= off) iw += u;
        }
        wtot[lane] = iw - w;   // exclusive
    }
    __syncthreads();
    int excl = inc - v + ((t < 512) ? wtot[wave] : 0);
    __syncthreads();
    if (t < 512) {
        sdeg[t] = excl;        // becomes local write pointer
        int node = nodes0 + t;
        if (node < NN) row_ptr[node] = baseS + excl;
    }
    __syncthreads();
    for (int i = t; i < cnt; i += 1024) {
        int2 e = eb[i];
        int pos = atomicAdd(&sdeg[e.y & 511], 1);
        esrc[baseS + pos] = e.x;
    }
    if (b == 0 && t == 0) row_ptr[NN] = EP;
}

// ---------------------------------------------------------------------------
// prep: gemm1 A-fragment image (17 tiles; tile 16 = va computed inline)
// + W2 bf16 cast. One kernel.
// ---------------------------------------------------------------------------
__global__ void k_prepfw(const float* __restrict__ W1, const float* __restrict__ a1s,
                         const float* __restrict__ a1d, const float* __restrict__ W2,
                         unsigned short* __restrict__ w1frag,
                         unsigned short* __restrict__ W2b) {
    int i = blockIdx.x * 256 + threadIdx.x;
    if (i < 17 * 2048) {
        int j = i & 7, lane = (i >> 3) & 63, s = (i >> 9) & 3, c = i >> 11;
        int q = lane >> 4, m = lane & 15;
        int k = s * 32 + q * 8 + j;
        float val;
        if (c < 16) {
            val = W1[k * C1 + c * 16 + m];
        } else {
            int h = m & 7;
            const float* av = (m < 8) ? a1s : a1d;
            float acc = 0.f;
            #pragma unroll
            for (int j2 = 0; j2 < 32; j2++)
                acc += W1[k * C1 + h * 32 + j2] * av[h * 32 + j2];
            val = acc;
        }
        w1frag[i] = f2bf(val);
    } else if (i < 17 * 2048 + C1 * DOUT) {
        int j = i - 17 * 2048;
        W2b[j] = f2bf(W2[j]);
    }
}

// ---------------------------------------------------------------------------
// GEMM1 via MFMA (operand-swapped). Node-major h1b[node][256] epilogue +
// al1sd fp32 [node][16] (0-7 src, 8-15 dst) + packed bf16 al1s8[node][8].
// ---------------------------------------------------------------------------
__global__ __launch_bounds__(256) void k_gemm1(const float* __restrict__ x,
                                               const unsigned short* __restrict__ w1frag,
                                               unsigned short* __restrict__ h1b,
                                               float* __restrict__ al1sd,
                                               unsigned short* __restrict__ al1s8) {
    int wid = (blockIdx.x * 256 + threadIdx.x) >> 6;
    int lane = threadIdx.x & 63;
    if (wid >= NW1) return;
    int nb = wid * 16;
    int m = lane & 15, quad = lane >> 4;
    const float* xrow = x + (nb + m) * DIN;

    float4 xf[8];
    #pragma unroll
    for (int s = 0; s < 4; s++) {
        xf[2 * s]     = *(const float4*)(xrow + s * 32 + quad * 8);
        xf[2 * s + 1] = *(const float4*)(xrow + s * 32 + quad * 8 + 4);
    }
    short8 bfr[4];
    #pragma unroll
    for (int s = 0; s < 4; s++) {
        unsigned short* bp = (unsigned short*)&bfr[s];
        float4 f0 = xf[2 * s], f1 = xf[2 * s + 1];
        bp[0] = f2bf(f0.x); bp[1] = f2bf(f0.y); bp[2] = f2bf(f0.z); bp[3] = f2bf(f0.w);
        bp[4] = f2bf(f1.x); bp[5] = f2bf(f1.y); bp[6] = f2bf(f1.z); bp[7] = f2bf(f1.w);
    }

    float4v acc[17];
    #pragma unroll
    for (int c = 0; c < 17; c++) acc[c] = (float4v){0.f, 0.f, 0.f, 0.f};

    #pragma unroll
    for (int s = 0; s < 4; s++) {
        const unsigned short* fp = w1frag + (s * 64 + lane) * 8;
        #pragma unroll
        for (int c = 0; c < 17; c++) {
            short8 afrag = *(const short8*)(fp + c * 2048);
            acc[c] = __builtin_amdgcn_mfma_f32_16x16x32_bf16(afrag, bfr[s], acc[c], 0, 0, 0);
        }
    }

    int node = nb + m;
    #pragma unroll
    for (int c = 0; c < 16; c++) {
        uint2 pk;
        pk.x = (unsigned)f2bf(acc[c][0]) | ((unsigned)f2bf(acc[c][1]) << 16);
        pk.y = (unsigned)f2bf(acc[c][2]) | ((unsigned)f2bf(acc[c][3]) << 16);
        *(uint2*)(h1b + node * C1 + c * 16 + quad * 4) = pk;
    }
    *(float4*)(al1sd + node * 16 + quad * 4) =
        make_float4(acc[16][0], acc[16][1], acc[16][2], acc[16][3]);
    if (quad < 2) {   // src logits (rows 0-7) packed bf16
        uint2 pk;
        pk.x = (unsigned)f2bf(acc[16][0]) | ((unsigned)f2bf(acc[16][1]) << 16);
        pk.y = (unsigned)f2bf(acc[16][2]) | ((unsigned)f2bf(acc[16][3]) << 16);
        *(uint2*)(al1s8 + node * 8 + quad * 4) = pk;
    }
}

// ---------------------------------------------------------------------------
// agg1 (R5 winner structure): one wave per dst node, two-phase, node range
// [n0, n0+25000).
// ---------------------------------------------------------------------------
__global__ __launch_bounds__(256) void k_agg1(const int* __restrict__ row_ptr,
                                              const int* __restrict__ esrc,
                                              const unsigned short* __restrict__ h1b,
                                              const unsigned short* __restrict__ al1s8,
                                              const float* __restrict__ al1sd,
                                              const float* __restrict__ b1,
                                              unsigned short* __restrict__ helu_b,
                                              int n0) {
    __shared__ float wbuf[4][64 * 8];
    __shared__ int   sbuf[4][64];
    int wslot = threadIdx.x >> 6;
    int L = threadIdx.x & 63;
    int d = n0 + ((blockIdx.x * 256 + threadIdx.x) >> 6);
    int h = L >> 3;
    int start = row_ptr[d], end = row_ptr[d + 1];
    float4 ald0 = *(const float4*)(al1sd + d * 16 + 8);
    float4 ald1 = *(const float4*)(al1sd + d * 16 + 12);
    float* wrow = wbuf[wslot];
    int* srow = sbuf[wslot];
    float denom = 0.f;
    float4 acc = make_float4(0.f, 0.f, 0.f, 0.f);
    const int Lofs = L * 4;

    for (int base = start; base < end; base += 64) {
        int cnt = min(64, end - base);
        int s = d;
        float wv0 = 0.f, wv1 = 0.f, wv2 = 0.f, wv3 = 0.f;
        float wv4 = 0.f, wv5 = 0.f, wv6 = 0.f, wv7 = 0.f;
        if (L < cnt) {
            s = esrc[base + L];
            uint4 as = *(const uint4*)(al1s8 + s * 8);
            float e;
            e = bflo(as.x) + ald0.x; e = e > 0.f ? e : 0.2f * e; wv0 = __expf(e);
            e = bfhi(as.x) + ald0.y; e = e > 0.f ? e : 0.2f * e; wv1 = __expf(e);
            e = bflo(as.y) + ald0.z; e = e > 0.f ? e : 0.2f * e; wv2 = __expf(e);
            e = bfhi(as.y) + ald0.w; e = e > 0.f ? e : 0.2f * e; wv3 = __expf(e);
            e = bflo(as.z) + ald1.x; e = e > 0.f ? e : 0.2f * e; wv4 = __expf(e);
            e = bfhi(as.z) + ald1.y; e = e > 0.f ? e : 0.2f * e; wv5 = __expf(e);
            e = bflo(as.w) + ald1.z; e = e > 0.f ? e : 0.2f * e; wv6 = __expf(e);
            e = bfhi(as.w) + ald1.w; e = e > 0.f ? e : 0.2f * e; wv7 = __expf(e);
        }
        srow[L] = s;
        *(float4*)&wrow[L * 8]     = make_float4(wv0, wv1, wv2, wv3);
        *(float4*)&wrow[L * 8 + 4] = make_float4(wv4, wv5, wv6, wv7);
        int cnt4 = (cnt + 3) & ~3;
        for (int i = 0; i < cnt4; i += 4) {
            int s0 = srow[i], s1 = srow[i + 1], s2 = srow[i + 2], s3 = srow[i + 3];
            float x0 = wrow[i * 8 + h];
            float x1 = wrow[i * 8 + 8 + h];
            float x2 = wrow[i * 8 + 16 + h];
            float x3 = wrow[i * 8 + 24 + h];
            uint2 v0 = *(const uint2*)(h1b + s0 * C1 + Lofs);
            uint2 v1 = *(const uint2*)(h1b + s1 * C1 + Lofs);
            uint2 v2 = *(const uint2*)(h1b + s2 * C1 + Lofs);
            uint2 v3 = *(const uint2*)(h1b + s3 * C1 + Lofs);
            denom += (x0 + x1) + (x2 + x3);
            acc.x += x0 * bflo(v0.x); acc.y += x0 * bfhi(v0.x);
            acc.z += x0 * bflo(v0.y); acc.w += x0 * bfhi(v0.y);
            acc.x += x1 * bflo(v1.x); acc.y += x1 * bfhi(v1.x);
            acc.z += x1 * bflo(v1.y); acc.w += x1 * bfhi(v1.y);
            acc.x += x2 * bflo(v2.x); acc.y += x2 * bfhi(v2.x);
            acc.z += x2 * bflo(v2.y); acc.w += x2 * bfhi(v2.y);
            acc.x += x3 * bflo(v3.x); acc.y += x3 * bfhi(v3.x);
            acc.z += x3 * bflo(v3.y); acc.w += x3 * bfhi(v3.y);
        }
    }
    float inv = 1.0f / (denom + 1e-16f);
    float4 bv = *(const float4*)(b1 + Lofs);
    float o0 = acc.x * inv + bv.x;
    float o1 = acc.y * inv + bv.y;
    float o2 = acc.z * inv + bv.z;
    float o3 = acc.w * inv + bv.w;
    o0 = o0 > 0.f ? o0 : __expf(o0) - 1.0f;
    o1 = o1 > 0.f ? o1 : __expf(o1) - 1.0f;
    o2 = o2 > 0.f ? o2 : __expf(o2) - 1.0f;
    o3 = o3 > 0.f ? o3 : __expf(o3) - 1.0f;
    uint2 pk;
    pk.x = (unsigned)f2bf(o0) | ((unsigned)f2bf(o1) << 16);
    pk.y = (unsigned)f2bf(o2) | ((unsigned)f2bf(o3) << 16);
    *(uint2*)(helu_b + d * C1 + Lofs) = pk;
}

// ---------------------------------------------------------------------------
// GEMM2 via MFMA 16x16x32 bf16 + fused al2 epilogue (unchanged).
// ---------------------------------------------------------------------------
__global__ __launch_bounds__(256) void k_gemm2(const unsigned short* __restrict__ helu_b,
                                               const unsigned short* __restrict__ W2b,
                                               const float* __restrict__ a2s,
                                               const float* __restrict__ a2d,
                                               unsigned short* __restrict__ h2b,
                                               float* __restrict__ al2s,
                                               float* __restrict__ al2d) {
    int wid = (blockIdx.x * 256 + threadIdx.x) >> 6;
    int lane = threadIdx.x & 63;
    int nb = wid * 16;
    if (nb >= NN) return;
    int m = lane & 15, quad = lane >> 4;

    short8 bfrag[8];
    #pragma unroll
    for (int s = 0; s < 8; s++) {
        #pragma unroll
        for (int j = 0; j < 8; j++) {
            ((short*)&bfrag[s])[j] = (short)W2b[(s * 32 + quad * 8 + j) * DOUT + m];
        }
    }

    float4v acc = {0.f, 0.f, 0.f, 0.f};
    const unsigned short* arow = helu_b + (nb + m) * C1 + quad * 8;
    #pragma unroll
    for (int s = 0; s < 8; s++) {
        short8 afrag = *(const short8*)(arow + s * 32);
        acc = __builtin_amdgcn_mfma_f32_16x16x32_bf16(afrag, bfrag[s], acc, 0, 0, 0);
    }

    float as_c = a2s[m], ad_c = a2d[m];
    #pragma unroll
    for (int r = 0; r < 4; r++) {
        int node = nb + quad * 4 + r;
        float val = acc[r];
        h2b[node * DOUT + m] = f2bf(val);
        float ps = val * as_c;
        float pd = val * ad_c;
        ps += __shfl_xor(ps, 1, 64); ps += __shfl_xor(ps, 2, 64);
        ps += __shfl_xor(ps, 4, 64); ps += __shfl_xor(ps, 8, 64);
        pd += __shfl_xor(pd, 1, 64); pd += __shfl_xor(pd, 2, 64);
        pd += __shfl_xor(pd, 4, 64); pd += __shfl_xor(pd, 8, 64);
        if (m == 0) {
            al2s[node] = ps;
            al2d[node] = pd;
        }
    }
}

// ---------------------------------------------------------------------------
// agg2 + bias + log_softmax (unchanged two-phase).
// ---------------------------------------------------------------------------
__global__ __launch_bounds__(256) void k_agg2(const int* __restrict__ row_ptr,
                                              const int* __restrict__ esrc,
                                              const unsigned short* __restrict__ h2b,
                                              const float* __restrict__ al2s,
                                              const float* __restrict__ al2d,
                                              const float* __restrict__ b2,
                                              float* __restrict__ out) {
    __shared__ float wbuf2[4][64];
    __shared__ int   sbuf2[4][64];
    int wslot = threadIdx.x >> 6;
    int L = threadIdx.x & 63;
    int n = (blockIdx.x * 256 + threadIdx.x) >> 6;
    if (n >= NN) return;
    int c = L & 15, g = L >> 4;
    int start = row_ptr[n], end = row_ptr[n + 1];
    float ald = al2d[n];
    float* wrow = wbuf2[wslot];
    int* srow = sbuf2[wslot];
    float acc = 0.f, denom = 0.f;

    for (int base = start; base < end; base += 64) {
        int cnt = min(64, end - base);
        int s = n; float w = 0.f;
        if (L < cnt) {
            s = esrc[base + L];
            float e = al2s[s] + ald;
            e = e > 0.f ? e : 0.2f * e;
            w = __expf(e);
        }
        srow[L] = s;
        wrow[L] = w;
        int cnt4 = (cnt + 3) & ~3;
        for (int i = 0; i < cnt4; i += 4) {
            int idx = i + g;
            int ss = srow[idx];
            float ww = wrow[idx];
            float v = bf2f(h2b[ss * DOUT + c]);
            acc += ww * v;
            denom += ww;
        }
    }
    acc += __shfl_xor(acc, 16, 64);   acc += __shfl_xor(acc, 32, 64);
    denom += __shfl_xor(denom, 16, 64); denom += __shfl_xor(denom, 32, 64);
    float val = acc / (denom + 1e-16f) + b2[c];
    float m = val;
    #pragma unroll
    for (int mm = 1; mm < 16; mm <<= 1) m = fmaxf(m, __shfl_xor(m, mm, 64));
    float ex = __expf(val - m);
    float se = ex;
    #pragma unroll
    for (int mm = 1; mm < 16; mm <<= 1) se += __shfl_xor(se, mm, 64);
    if (L < 16) out[n * DOUT + c] = val - m - __logf(se);
}

// ---------------------------------------------------------------------------
extern "C" void kernel_launch(void* const* d_in, const int* in_sizes, int n_in,
                              void* d_out, int out_size, void* d_ws, size_t ws_size,
                              hipStream_t stream) {
    const float* x   = (const float*)d_in[0];
    const int*   ei  = (const int*)d_in[1];
    const float* W1  = (const float*)d_in[2];
    const float* a1s = (const float*)d_in[3];
    const float* a1d = (const float*)d_in[4];
    const float* b1  = (const float*)d_in[5];
    const float* W2  = (const float*)d_in[6];
    const float* a2s = (const float*)d_in[7];
    const float* a2d = (const float*)d_in[8];
    const float* b2  = (const float*)d_in[9];
    float* outp = (float*)d_out;

    // workspace layout
    unsigned short* h1b    = (unsigned short*)d_ws;      // N*256 bf16 node-major
    unsigned short* helu_b = h1b + NN * C1;              // N*256 bf16
    unsigned short* h2b    = helu_b + NN * C1;           // N*16 bf16
    unsigned short* W2b    = h2b + NN * DOUT;            // 4096 bf16
    unsigned short* w1frag = W2b + C1 * DOUT;            // 34816 bf16
    unsigned short* al1s8  = w1frag + 17 * 2048;         // N*8 bf16 (src logits)
    float* al1sd = (float*)(al1s8 + NN * 8);             // N*16 fp32
    float* al2sb = al1sd + NN * 16;                      // N
    float* al2db = al2sb + NN;                           // N
    int* row_ptr = (int*)(al2db + NN);                   // N+1
    int* esrc    = row_ptr + NN + 1;                     // EP
    int* cntb    = esrc + EP;                            // NB
    // ebuf aliases helu_b (25.6 MB >= 12.85 MB needed); consumed by k_csr
    // before agg1 writes helu_b -- single-stream ordering guarantees safety.
    int2* ebuf   = (int2*)helu_b;                        // NB * CAP int2

    hipMemsetAsync(cntb, 0, NB * sizeof(int), stream);
    k_bucketA<<<(EP + BBLK - 1) / BBLK, 256, 0, stream>>>(ei, cntb, ebuf);
    k_csr<<<NB, 1024, 0, stream>>>(cntb, ebuf, row_ptr, esrc);

    k_prepfw<<<(17 * 2048 + C1 * DOUT + 255) / 256, 256, 0, stream>>>(W1, a1s, a1d, W2, w1frag, W2b);
    k_gemm1<<<(NW1 * 64 + 255) / 256, 256, 0, stream>>>(x, w1frag, h1b, al1sd, al1s8);
    k_agg1<<<25000 / 4, 256, 0, stream>>>(row_ptr, esrc, h1b, al1s8, al1sd, b1, helu_b, 0);
    k_agg1<<<25000 / 4, 256, 0, stream>>>(row_ptr, esrc, h1b, al1s8, al1sd, b1, helu_b, 25000);

    k_gemm2<<<(NW1 * 64 + 255) / 256, 256, 0, stream>>>(helu_b, W2b, a2s, a2d, h2b, al2sb, al2db);
    k_agg2<<<(NN * 64 + 255) / 256, 256, 0, stream>>>(row_ptr, esrc, h2b, al2sb, al2db, b2, outp);
}

// Round 11
// 238.818 us; speedup vs baseline: 1.7761x; 1.0147x over previous
//
#include <hip/hip_runtime.h>
#include <hip/hip_bf16.h>

// Problem constants (match reference)
#define NN 50000
#define EE 800000
#define EP (EE + NN)        // edges + self loops = 850000
#define DIN 128
#define HID 32
#define HEADS 8
#define C1 (HEADS * HID)    // 256
#define DOUT 16
#define NW1 3125            // gemm1/gemm2 waves: 50000/16
#define SH 9                // bucket shift: 512 nodes/bucket
#define NB 98               // ceil(50000/512)
#define CAP 16384           // per-bucket ebuf capacity (mean 8704, sigma~90)
#define EPT 8               // edges per thread in k_bucketA
#define BBLK (256 * EPT)    // 2048 edges per block

typedef __attribute__((ext_vector_type(8))) short short8;   // 8 bf16 (4 VGPRs)
typedef __attribute__((ext_vector_type(4))) float float4v;  // MFMA C/D

__device__ inline unsigned short f2bf(float f) {
    __hip_bfloat16 b = __float2bfloat16(f);
    return *reinterpret_cast<unsigned short*>(&b);
}
__device__ inline float bf2f(unsigned short u) {
    union { unsigned int i; float f; } x;
    x.i = ((unsigned int)u) << 16;
    return x.f;
}
__device__ inline float bflo(unsigned u) {
    union { unsigned int i; float f; } x;
    x.i = u << 16;
    return x.f;
}
__device__ inline float bfhi(unsigned u) {
    union { unsigned int i; float f; } x;
    x.i = u & 0xffff0000u;
    return x.f;
}

// ---------------------------------------------------------------------------
// CSR pass 1: bucket edges by dst>>9 into per-bucket regions of ebuf.
// LDS histogram; ONE global atomic per (block,bucket); self-loops folded in.
// ---------------------------------------------------------------------------
__global__ __launch_bounds__(256) void k_bucketA(const int* __restrict__ ei,
                                                 int* __restrict__ cntb,
                                                 int2* __restrict__ ebuf) {
    __shared__ int hist[NB];
    __shared__ int base[NB];
    int t = threadIdx.x;
    if (t < NB) hist[t] = 0;
    __syncthreads();
    int e0 = blockIdx.x * BBLK;
    int s[EPT], d[EPT], r[EPT];
    #pragma unroll
    for (int j = 0; j < EPT; j++) {
        int e = e0 + j * 256 + t;
        int ss = 0, dd = -1;
        if (e < EE) { ss = ei[e]; dd = ei[EE + e]; }
        else if (e < EP) { ss = e - EE; dd = ss; }   // self loop
        s[j] = ss; d[j] = dd;
        if (dd >= 0) r[j] = atomicAdd(&hist[dd >> SH], 1);
    }
    __syncthreads();
    if (t < NB) base[t] = hist[t] ? atomicAdd(&cntb[t], hist[t]) : 0;
    __syncthreads();
    #pragma unroll
    for (int j = 0; j < EPT; j++) {
        if (d[j] >= 0) {
            int b = d[j] >> SH;
            ebuf[b * CAP + base[b] + r[j]] = make_int2(s[j], d[j]);
        }
    }
}

// ---------------------------------------------------------------------------
// CSR pass 2: one block per bucket. LDS degree count -> LDS scan ->
// row_ptr write -> LDS-atomic rank scatter into the bucket's exclusive
// ~35 KB esrc window (single CU => full L2 line fill). Zero global atomics.
// ---------------------------------------------------------------------------
__global__ __launch_bounds__(1024) void k_csr(const int* __restrict__ cntb,
                                              const int2* __restrict__ ebuf,
                                              int* __restrict__ row_ptr,
                                              int* __restrict__ esrc) {
    __shared__ int sdeg[512];
    __shared__ int wtot[8];
    __shared__ int bpart[2];
    int b = blockIdx.x;
    int t = threadIdx.x;
    int lane = t & 63, wave = t >> 6;
    int nodes0 = b << SH;
    if (t < 512) sdeg[t] = 0;
    if (t < 128) {   // baseS = sum cntb[0..b-1] (two-wave butterfly sum)
        int v = (t < b) ? cntb[t] : 0;
        #pragma unroll
        for (int off = 1; off < 64; off <<= 1) v += __shfl_xor(v, off, 64);
        if (lane == 0) bpart[wave] = v;
    }
    __syncthreads();
    int baseS = bpart[0] + bpart[1];
    int cnt = cntb[b];
    const int2* eb = ebuf + b * CAP;
    for (int i = t; i < cnt; i += 1024)
        atomicAdd(&sdeg[eb[i].y & 511], 1);
    __syncthreads();
    int v = (t < 512) ? sdeg[t] : 0;
    int inc = v;
    #pragma unroll
    for (int off = 1; off < 64; off <<= 1) {
        int u = __shfl_up(inc, off, 64);
        if (lane >= off) inc += u;
    }
    if (t < 512 && lane == 63) wtot[wave] = inc;
    __syncthreads();
    if (wave == 0 && lane < 8) {
        int w = wtot[lane];
        int iw = w;
        #pragma unroll
        for (int off = 1; off < 8; off <<= 1) {
            int u = __shfl_up(iw, off, 64);
            if (lane >= off) iw += u;
        }
        wtot[lane] = iw - w;   // exclusive
    }
    __syncthreads();
    int excl = inc - v + ((t < 512) ? wtot[wave] : 0);
    __syncthreads();
    if (t < 512) {
        sdeg[t] = excl;        // becomes local write pointer
        int node = nodes0 + t;
        if (node < NN) row_ptr[node] = baseS + excl;
    }
    __syncthreads();
    for (int i = t; i < cnt; i += 1024) {
        int2 e = eb[i];
        int pos = atomicAdd(&sdeg[e.y & 511], 1);
        esrc[baseS + pos] = e.x;
    }
    if (b == 0 && t == 0) row_ptr[NN] = EP;
}

// ---------------------------------------------------------------------------
// prep: gemm1 A-fragment image (17 tiles; tile 16 = va computed inline)
// + W2 bf16 cast. One kernel.
// ---------------------------------------------------------------------------
__global__ void k_prepfw(const float* __restrict__ W1, const float* __restrict__ a1s,
                         const float* __restrict__ a1d, const float* __restrict__ W2,
                         unsigned short* __restrict__ w1frag,
                         unsigned short* __restrict__ W2b) {
    int i = blockIdx.x * 256 + threadIdx.x;
    if (i < 17 * 2048) {
        int j = i & 7, lane = (i >> 3) & 63, s = (i >> 9) & 3, c = i >> 11;
        int q = lane >> 4, m = lane & 15;
        int k = s * 32 + q * 8 + j;
        float val;
        if (c < 16) {
            val = W1[k * C1 + c * 16 + m];
        } else {
            int h = m & 7;
            const float* av = (m < 8) ? a1s : a1d;
            float acc = 0.f;
            #pragma unroll
            for (int j2 = 0; j2 < 32; j2++)
                acc += W1[k * C1 + h * 32 + j2] * av[h * 32 + j2];
            val = acc;
        }
        w1frag[i] = f2bf(val);
    } else if (i < 17 * 2048 + C1 * DOUT) {
        int j = i - 17 * 2048;
        W2b[j] = f2bf(W2[j]);
    }
}

// ---------------------------------------------------------------------------
// GEMM1 via MFMA (operand-swapped). Node-major h1b[node][256] epilogue +
// al1sd fp32 [node][16] (0-7 src, 8-15 dst) + packed bf16 al1s8[node][8].
// ---------------------------------------------------------------------------
__global__ __launch_bounds__(256) void k_gemm1(const float* __restrict__ x,
                                               const unsigned short* __restrict__ w1frag,
                                               unsigned short* __restrict__ h1b,
                                               float* __restrict__ al1sd,
                                               unsigned short* __restrict__ al1s8) {
    int wid = (blockIdx.x * 256 + threadIdx.x) >> 6;
    int lane = threadIdx.x & 63;
    if (wid >= NW1) return;
    int nb = wid * 16;
    int m = lane & 15, quad = lane >> 4;
    const float* xrow = x + (nb + m) * DIN;

    float4 xf[8];
    #pragma unroll
    for (int s = 0; s < 4; s++) {
        xf[2 * s]     = *(const float4*)(xrow + s * 32 + quad * 8);
        xf[2 * s + 1] = *(const float4*)(xrow + s * 32 + quad * 8 + 4);
    }
    short8 bfr[4];
    #pragma unroll
    for (int s = 0; s < 4; s++) {
        unsigned short* bp = (unsigned short*)&bfr[s];
        float4 f0 = xf[2 * s], f1 = xf[2 * s + 1];
        bp[0] = f2bf(f0.x); bp[1] = f2bf(f0.y); bp[2] = f2bf(f0.z); bp[3] = f2bf(f0.w);
        bp[4] = f2bf(f1.x); bp[5] = f2bf(f1.y); bp[6] = f2bf(f1.z); bp[7] = f2bf(f1.w);
    }

    float4v acc[17];
    #pragma unroll
    for (int c = 0; c < 17; c++) acc[c] = (float4v){0.f, 0.f, 0.f, 0.f};

    #pragma unroll
    for (int s = 0; s < 4; s++) {
        const unsigned short* fp = w1frag + (s * 64 + lane) * 8;
        #pragma unroll
        for (int c = 0; c < 17; c++) {
            short8 afrag = *(const short8*)(fp + c * 2048);
            acc[c] = __builtin_amdgcn_mfma_f32_16x16x32_bf16(afrag, bfr[s], acc[c], 0, 0, 0);
        }
    }

    int node = nb + m;
    #pragma unroll
    for (int c = 0; c < 16; c++) {
        uint2 pk;
        pk.x = (unsigned)f2bf(acc[c][0]) | ((unsigned)f2bf(acc[c][1]) << 16);
        pk.y = (unsigned)f2bf(acc[c][2]) | ((unsigned)f2bf(acc[c][3]) << 16);
        *(uint2*)(h1b + node * C1 + c * 16 + quad * 4) = pk;
    }
    *(float4*)(al1sd + node * 16 + quad * 4) =
        make_float4(acc[16][0], acc[16][1], acc[16][2], acc[16][3]);
    if (quad < 2) {   // src logits (rows 0-7) packed bf16
        uint2 pk;
        pk.x = (unsigned)f2bf(acc[16][0]) | ((unsigned)f2bf(acc[16][1]) << 16);
        pk.y = (unsigned)f2bf(acc[16][2]) | ((unsigned)f2bf(acc[16][3]) << 16);
        *(uint2*)(al1s8 + node * 8 + quad * 4) = pk;
    }
}

// ---------------------------------------------------------------------------
// agg1 (R5 winner structure, SINGLE launch): one wave per dst node,
// two-phase. Phase 1: lane e computes all 8 head-weights of edge e (al1s8
// bf16 row = one 16 B load). Phase 2: 4 edges in flight, 512 B/edge.
// NOTE: do NOT split into node-range halves -- each half re-pays the full
// compulsory per-XCD fetch of the 25.6 MB h1b table (~2x fabric traffic,
// measured +45 us in R8-R10).
// ---------------------------------------------------------------------------
__global__ __launch_bounds__(256) void k_agg1(const int* __restrict__ row_ptr,
                                              const int* __restrict__ esrc,
                                              const unsigned short* __restrict__ h1b,
                                              const unsigned short* __restrict__ al1s8,
                                              const float* __restrict__ al1sd,
                                              const float* __restrict__ b1,
                                              unsigned short* __restrict__ helu_b) {
    __shared__ float wbuf[4][64 * 8];
    __shared__ int   sbuf[4][64];
    int wslot = threadIdx.x >> 6;
    int L = threadIdx.x & 63;
    int d = (blockIdx.x * 256 + threadIdx.x) >> 6;
    int h = L >> 3;
    int start = row_ptr[d], end = row_ptr[d + 1];
    float4 ald0 = *(const float4*)(al1sd + d * 16 + 8);
    float4 ald1 = *(const float4*)(al1sd + d * 16 + 12);
    float* wrow = wbuf[wslot];
    int* srow = sbuf[wslot];
    float denom = 0.f;
    float4 acc = make_float4(0.f, 0.f, 0.f, 0.f);
    const int Lofs = L * 4;

    for (int base = start; base < end; base += 64) {
        int cnt = min(64, end - base);
        int s = d;
        float wv0 = 0.f, wv1 = 0.f, wv2 = 0.f, wv3 = 0.f;
        float wv4 = 0.f, wv5 = 0.f, wv6 = 0.f, wv7 = 0.f;
        if (L < cnt) {
            s = esrc[base + L];
            uint4 as = *(const uint4*)(al1s8 + s * 8);
            float e;
            e = bflo(as.x) + ald0.x; e = e > 0.f ? e : 0.2f * e; wv0 = __expf(e);
            e = bfhi(as.x) + ald0.y; e = e > 0.f ? e : 0.2f * e; wv1 = __expf(e);
            e = bflo(as.y) + ald0.z; e = e > 0.f ? e : 0.2f * e; wv2 = __expf(e);
            e = bfhi(as.y) + ald0.w; e = e > 0.f ? e : 0.2f * e; wv3 = __expf(e);
            e = bflo(as.z) + ald1.x; e = e > 0.f ? e : 0.2f * e; wv4 = __expf(e);
            e = bfhi(as.z) + ald1.y; e = e > 0.f ? e : 0.2f * e; wv5 = __expf(e);
            e = bflo(as.w) + ald1.z; e = e > 0.f ? e : 0.2f * e; wv6 = __expf(e);
            e = bfhi(as.w) + ald1.w; e = e > 0.f ? e : 0.2f * e; wv7 = __expf(e);
        }
        srow[L] = s;
        *(float4*)&wrow[L * 8]     = make_float4(wv0, wv1, wv2, wv3);
        *(float4*)&wrow[L * 8 + 4] = make_float4(wv4, wv5, wv6, wv7);
        int cnt4 = (cnt + 3) & ~3;
        for (int i = 0; i < cnt4; i += 4) {
            int s0 = srow[i], s1 = srow[i + 1], s2 = srow[i + 2], s3 = srow[i + 3];
            float x0 = wrow[i * 8 + h];
            float x1 = wrow[i * 8 + 8 + h];
            float x2 = wrow[i * 8 + 16 + h];
            float x3 = wrow[i * 8 + 24 + h];
            uint2 v0 = *(const uint2*)(h1b + s0 * C1 + Lofs);
            uint2 v1 = *(const uint2*)(h1b + s1 * C1 + Lofs);
            uint2 v2 = *(const uint2*)(h1b + s2 * C1 + Lofs);
            uint2 v3 = *(const uint2*)(h1b + s3 * C1 + Lofs);
            denom += (x0 + x1) + (x2 + x3);
            acc.x += x0 * bflo(v0.x); acc.y += x0 * bfhi(v0.x);
            acc.z += x0 * bflo(v0.y); acc.w += x0 * bfhi(v0.y);
            acc.x += x1 * bflo(v1.x); acc.y += x1 * bfhi(v1.x);
            acc.z += x1 * bflo(v1.y); acc.w += x1 * bfhi(v1.y);
            acc.x += x2 * bflo(v2.x); acc.y += x2 * bfhi(v2.x);
            acc.z += x2 * bflo(v2.y); acc.w += x2 * bfhi(v2.y);
            acc.x += x3 * bflo(v3.x); acc.y += x3 * bfhi(v3.x);
            acc.z += x3 * bflo(v3.y); acc.w += x3 * bfhi(v3.y);
        }
    }
    float inv = 1.0f / (denom + 1e-16f);
    float4 bv = *(const float4*)(b1 + Lofs);
    float o0 = acc.x * inv + bv.x;
    float o1 = acc.y * inv + bv.y;
    float o2 = acc.z * inv + bv.z;
    float o3 = acc.w * inv + bv.w;
    o0 = o0 > 0.f ? o0 : __expf(o0) - 1.0f;
    o1 = o1 > 0.f ? o1 : __expf(o1) - 1.0f;
    o2 = o2 > 0.f ? o2 : __expf(o2) - 1.0f;
    o3 = o3 > 0.f ? o3 : __expf(o3) - 1.0f;
    uint2 pk;
    pk.x = (unsigned)f2bf(o0) | ((unsigned)f2bf(o1) << 16);
    pk.y = (unsigned)f2bf(o2) | ((unsigned)f2bf(o3) << 16);
    *(uint2*)(helu_b + d * C1 + Lofs) = pk;
}

// ---------------------------------------------------------------------------
// GEMM2 via MFMA 16x16x32 bf16 + fused al2 epilogue (unchanged).
// ---------------------------------------------------------------------------
__global__ __launch_bounds__(256) void k_gemm2(const unsigned short* __restrict__ helu_b,
                                               const unsigned short* __restrict__ W2b,
                                               const float* __restrict__ a2s,
                                               const float* __restrict__ a2d,
                                               unsigned short* __restrict__ h2b,
                                               float* __restrict__ al2s,
                                               float* __restrict__ al2d) {
    int wid = (blockIdx.x * 256 + threadIdx.x) >> 6;
    int lane = threadIdx.x & 63;
    int nb = wid * 16;
    if (nb >= NN) return;
    int m = lane & 15, quad = lane >> 4;

    short8 bfrag[8];
    #pragma unroll
    for (int s = 0; s < 8; s++) {
        #pragma unroll
        for (int j = 0; j < 8; j++) {
            ((short*)&bfrag[s])[j] = (short)W2b[(s * 32 + quad * 8 + j) * DOUT + m];
        }
    }

    float4v acc = {0.f, 0.f, 0.f, 0.f};
    const unsigned short* arow = helu_b + (nb + m) * C1 + quad * 8;
    #pragma unroll
    for (int s = 0; s < 8; s++) {
        short8 afrag = *(const short8*)(arow + s * 32);
        acc = __builtin_amdgcn_mfma_f32_16x16x32_bf16(afrag, bfrag[s], acc, 0, 0, 0);
    }

    float as_c = a2s[m], ad_c = a2d[m];
    #pragma unroll
    for (int r = 0; r < 4; r++) {
        int node = nb + quad * 4 + r;
        float val = acc[r];
        h2b[node * DOUT + m] = f2bf(val);
        float ps = val * as_c;
        float pd = val * ad_c;
        ps += __shfl_xor(ps, 1, 64); ps += __shfl_xor(ps, 2, 64);
        ps += __shfl_xor(ps, 4, 64); ps += __shfl_xor(ps, 8, 64);
        pd += __shfl_xor(pd, 1, 64); pd += __shfl_xor(pd, 2, 64);
        pd += __shfl_xor(pd, 4, 64); pd += __shfl_xor(pd, 8, 64);
        if (m == 0) {
            al2s[node] = ps;
            al2d[node] = pd;
        }
    }
}

// ---------------------------------------------------------------------------
// agg2 + bias + log_softmax (unchanged two-phase).
// ---------------------------------------------------------------------------
__global__ __launch_bounds__(256) void k_agg2(const int* __restrict__ row_ptr,
                                              const int* __restrict__ esrc,
                                              const unsigned short* __restrict__ h2b,
                                              const float* __restrict__ al2s,
                                              const float* __restrict__ al2d,
                                              const float* __restrict__ b2,
                                              float* __restrict__ out) {
    __shared__ float wbuf2[4][64];
    __shared__ int   sbuf2[4][64];
    int wslot = threadIdx.x >> 6;
    int L = threadIdx.x & 63;
    int n = (blockIdx.x * 256 + threadIdx.x) >> 6;
    if (n >= NN) return;
    int c = L & 15, g = L >> 4;
    int start = row_ptr[n], end = row_ptr[n + 1];
    float ald = al2d[n];
    float* wrow = wbuf2[wslot];
    int* srow = sbuf2[wslot];
    float acc = 0.f, denom = 0.f;

    for (int base = start; base < end; base += 64) {
        int cnt = min(64, end - base);
        int s = n; float w = 0.f;
        if (L < cnt) {
            s = esrc[base + L];
            float e = al2s[s] + ald;
            e = e > 0.f ? e : 0.2f * e;
            w = __expf(e);
        }
        srow[L] = s;
        wrow[L] = w;
        int cnt4 = (cnt + 3) & ~3;
        for (int i = 0; i < cnt4; i += 4) {
            int idx = i + g;
            int ss = srow[idx];
            float ww = wrow[idx];
            float v = bf2f(h2b[ss * DOUT + c]);
            acc += ww * v;
            denom += ww;
        }
    }
    acc += __shfl_xor(acc, 16, 64);   acc += __shfl_xor(acc, 32, 64);
    denom += __shfl_xor(denom, 16, 64); denom += __shfl_xor(denom, 32, 64);
    float val = acc / (denom + 1e-16f) + b2[c];
    float m = val;
    #pragma unroll
    for (int mm = 1; mm < 16; mm <<= 1) m = fmaxf(m, __shfl_xor(m, mm, 64));
    float ex = __expf(val - m);
    float se = ex;
    #pragma unroll
    for (int mm = 1; mm < 16; mm <<= 1) se += __shfl_xor(se, mm, 64);
    if (L < 16) out[n * DOUT + c] = val - m - __logf(se);
}

// ---------------------------------------------------------------------------
extern "C" void kernel_launch(void* const* d_in, const int* in_sizes, int n_in,
                              void* d_out, int out_size, void* d_ws, size_t ws_size,
                              hipStream_t stream) {
    const float* x   = (const float*)d_in[0];
    const int*   ei  = (const int*)d_in[1];
    const float* W1  = (const float*)d_in[2];
    const float* a1s = (const float*)d_in[3];
    const float* a1d = (const float*)d_in[4];
    const float* b1  = (const float*)d_in[5];
    const float* W2  = (const float*)d_in[6];
    const float* a2s = (const float*)d_in[7];
    const float* a2d = (const float*)d_in[8];
    const float* b2  = (const float*)d_in[9];
    float* outp = (float*)d_out;

    // workspace layout
    unsigned short* h1b    = (unsigned short*)d_ws;      // N*256 bf16 node-major
    unsigned short* helu_b = h1b + NN * C1;              // N*256 bf16
    unsigned short* h2b    = helu_b + NN * C1;           // N*16 bf16
    unsigned short* W2b    = h2b + NN * DOUT;            // 4096 bf16
    unsigned short* w1frag = W2b + C1 * DOUT;            // 34816 bf16
    unsigned short* al1s8  = w1frag + 17 * 2048;         // N*8 bf16 (src logits)
    float* al1sd = (float*)(al1s8 + NN * 8);             // N*16 fp32
    float* al2sb = al1sd + NN * 16;                      // N
    float* al2db = al2sb + NN;                           // N
    int* row_ptr = (int*)(al2db + NN);                   // N+1
    int* esrc    = row_ptr + NN + 1;                     // EP
    int* cntb    = esrc + EP;                            // NB
    // ebuf aliases helu_b (25.6 MB >= 12.85 MB needed); consumed by k_csr
    // before agg1 writes helu_b -- single-stream ordering guarantees safety.
    int2* ebuf   = (int2*)helu_b;                        // NB * CAP int2

    hipMemsetAsync(cntb, 0, NB * sizeof(int), stream);
    k_bucketA<<<(EP + BBLK - 1) / BBLK, 256, 0, stream>>>(ei, cntb, ebuf);
    k_csr<<<NB, 1024, 0, stream>>>(cntb, ebuf, row_ptr, esrc);

    k_prepfw<<<(17 * 2048 + C1 * DOUT + 255) / 256, 256, 0, stream>>>(W1, a1s, a1d, W2, w1frag, W2b);
    k_gemm1<<<(NW1 * 64 + 255) / 256, 256, 0, stream>>>(x, w1frag, h1b, al1sd, al1s8);
    // SINGLE agg1 launch -- one compulsory per-XCD pass over h1b
    k_agg1<<<12500, 256, 0, stream>>>(row_ptr, esrc, h1b, al1s8, al1sd, b1, helu_b);

    k_gemm2<<<(NW1 * 64 + 255) / 256, 256, 0, stream>>>(helu_b, W2b, a2s, a2d, h2b, al2sb, al2db);
    k_agg2<<<(NN * 64 + 255) / 256, 256, 0, stream>>>(row_ptr, esrc, h2b, al2sb, al2db, b2, outp);
}

// Round 12
// 213.433 us; speedup vs baseline: 1.9874x; 1.1189x over previous
//
#include <hip/hip_runtime.h>
#include <hip/hip_bf16.h>

// Problem constants (match reference)
#define NN 50000
#define EE 800000
#define EP (EE + NN)        // edges + self loops = 850000
#define DIN 128
#define HID 32
#define HEADS 8
#define C1 (HEADS * HID)    // 256
#define DOUT 16
#define NW1 3125            // gemm1/gemm2 waves: 50000/16
#define SH 9                // bucket shift: 512 nodes/bucket
#define NB 98               // ceil(50000/512)
#define CAP 16384           // per-bucket ebuf capacity (mean 8704, sigma~90)
#define EPT 8               // edges per thread in k_bucketA
#define BBLK (256 * EPT)    // 2048 edges per block

typedef __attribute__((ext_vector_type(8))) short short8;   // 8 bf16 (4 VGPRs)
typedef __attribute__((ext_vector_type(4))) float float4v;  // MFMA C/D
typedef __attribute__((ext_vector_type(2))) float float2v;  // fp8 cvt result

__device__ inline unsigned short f2bf(float f) {
    __hip_bfloat16 b = __float2bfloat16(f);
    return *reinterpret_cast<unsigned short*>(&b);
}
__device__ inline float bf2f(unsigned short u) {
    union { unsigned int i; float f; } x;
    x.i = ((unsigned int)u) << 16;
    return x.f;
}
__device__ inline float bflo(unsigned u) {
    union { unsigned int i; float f; } x;
    x.i = u << 16;
    return x.f;
}
__device__ inline float bfhi(unsigned u) {
    union { unsigned int i; float f; } x;
    x.i = u & 0xffff0000u;
    return x.f;
}

// ---------------------------------------------------------------------------
// CSR pass 1: bucket edges by dst>>9 into per-bucket regions of ebuf.
// ---------------------------------------------------------------------------
__global__ __launch_bounds__(256) void k_bucketA(const int* __restrict__ ei,
                                                 int* __restrict__ cntb,
                                                 int2* __restrict__ ebuf) {
    __shared__ int hist[NB];
    __shared__ int base[NB];
    int t = threadIdx.x;
    if (t < NB) hist[t] = 0;
    __syncthreads();
    int e0 = blockIdx.x * BBLK;
    int s[EPT], d[EPT], r[EPT];
    #pragma unroll
    for (int j = 0; j < EPT; j++) {
        int e = e0 + j * 256 + t;
        int ss = 0, dd = -1;
        if (e < EE) { ss = ei[e]; dd = ei[EE + e]; }
        else if (e < EP) { ss = e - EE; dd = ss; }   // self loop
        s[j] = ss; d[j] = dd;
        if (dd >= 0) r[j] = atomicAdd(&hist[dd >> SH], 1);
    }
    __syncthreads();
    if (t < NB) base[t] = hist[t] ? atomicAdd(&cntb[t], hist[t]) : 0;
    __syncthreads();
    #pragma unroll
    for (int j = 0; j < EPT; j++) {
        if (d[j] >= 0) {
            int b = d[j] >> SH;
            ebuf[b * CAP + base[b] + r[j]] = make_int2(s[j], d[j]);
        }
    }
}

// ---------------------------------------------------------------------------
// CSR pass 2: one block per bucket; LDS count -> scan -> rank scatter.
// ---------------------------------------------------------------------------
__global__ __launch_bounds__(1024) void k_csr(const int* __restrict__ cntb,
                                              const int2* __restrict__ ebuf,
                                              int* __restrict__ row_ptr,
                                              int* __restrict__ esrc) {
    __shared__ int sdeg[512];
    __shared__ int wtot[8];
    __shared__ int bpart[2];
    int b = blockIdx.x;
    int t = threadIdx.x;
    int lane = t & 63, wave = t >> 6;
    int nodes0 = b << SH;
    if (t < 512) sdeg[t] = 0;
    if (t < 128) {
        int v = (t < b) ? cntb[t] : 0;
        #pragma unroll
        for (int off = 1; off < 64; off <<= 1) v += __shfl_xor(v, off, 64);
        if (lane == 0) bpart[wave] = v;
    }
    __syncthreads();
    int baseS = bpart[0] + bpart[1];
    int cnt = cntb[b];
    const int2* eb = ebuf + b * CAP;
    for (int i = t; i < cnt; i += 1024)
        atomicAdd(&sdeg[eb[i].y & 511], 1);
    __syncthreads();
    int v = (t < 512) ? sdeg[t] : 0;
    int inc = v;
    #pragma unroll
    for (int off = 1; off < 64; off <<= 1) {
        int u = __shfl_up(inc, off, 64);
        if (lane >= off) inc += u;
    }
    if (t < 512 && lane == 63) wtot[wave] = inc;
    __syncthreads();
    if (wave == 0 && lane < 8) {
        int w = wtot[lane];
        int iw = w;
        #pragma unroll
        for (int off = 1; off < 8; off <<= 1) {
            int u = __shfl_up(iw, off, 64);
            if (lane >= off) iw += u;
        }
        wtot[lane] = iw - w;   // exclusive
    }
    __syncthreads();
    int excl = inc - v + ((t < 512) ? wtot[wave] : 0);
    __syncthreads();
    if (t < 512) {
        sdeg[t] = excl;
        int node = nodes0 + t;
        if (node < NN) row_ptr[node] = baseS + excl;
    }
    __syncthreads();
    for (int i = t; i < cnt; i += 1024) {
        int2 e = eb[i];
        int pos = atomicAdd(&sdeg[e.y & 511], 1);
        esrc[baseS + pos] = e.x;
    }
    if (b == 0 && t == 0) row_ptr[NN] = EP;
}

// ---------------------------------------------------------------------------
// prep: gemm1 A-fragment image (17 tiles) + W2 bf16 cast.
// ---------------------------------------------------------------------------
__global__ void k_prepfw(const float* __restrict__ W1, const float* __restrict__ a1s,
                         const float* __restrict__ a1d, const float* __restrict__ W2,
                         unsigned short* __restrict__ w1frag,
                         unsigned short* __restrict__ W2b) {
    int i = blockIdx.x * 256 + threadIdx.x;
    if (i < 17 * 2048) {
        int j = i & 7, lane = (i >> 3) & 63, s = (i >> 9) & 3, c = i >> 11;
        int q = lane >> 4, m = lane & 15;
        int k = s * 32 + q * 8 + j;
        float val;
        if (c < 16) {
            val = W1[k * C1 + c * 16 + m];
        } else {
            int h = m & 7;
            const float* av = (m < 8) ? a1s : a1d;
            float acc = 0.f;
            #pragma unroll
            for (int j2 = 0; j2 < 32; j2++)
                acc += W1[k * C1 + h * 32 + j2] * av[h * 32 + j2];
            val = acc;
        }
        w1frag[i] = f2bf(val);
    } else if (i < 17 * 2048 + C1 * DOUT) {
        int j = i - 17 * 2048;
        W2b[j] = f2bf(W2[j]);
    }
}

// ---------------------------------------------------------------------------
// GEMM1 via MFMA (operand-swapped). Epilogue: h1 gather table stored as
// FP8 e4m3 (HW v_cvt_pk_fp8_f32) -- 12.8 MB, halves agg1 fetch traffic.
// Also al1sd fp32 [node][16] + packed bf16 al1s8[node][8] (src logits).
// ---------------------------------------------------------------------------
__global__ __launch_bounds__(256) void k_gemm1(const float* __restrict__ x,
                                               const unsigned short* __restrict__ w1frag,
                                               unsigned char* __restrict__ h1f8,
                                               float* __restrict__ al1sd,
                                               unsigned short* __restrict__ al1s8) {
    int wid = (blockIdx.x * 256 + threadIdx.x) >> 6;
    int lane = threadIdx.x & 63;
    if (wid >= NW1) return;
    int nb = wid * 16;
    int m = lane & 15, quad = lane >> 4;
    const float* xrow = x + (nb + m) * DIN;

    float4 xf[8];
    #pragma unroll
    for (int s = 0; s < 4; s++) {
        xf[2 * s]     = *(const float4*)(xrow + s * 32 + quad * 8);
        xf[2 * s + 1] = *(const float4*)(xrow + s * 32 + quad * 8 + 4);
    }
    short8 bfr[4];
    #pragma unroll
    for (int s = 0; s < 4; s++) {
        unsigned short* bp = (unsigned short*)&bfr[s];
        float4 f0 = xf[2 * s], f1 = xf[2 * s + 1];
        bp[0] = f2bf(f0.x); bp[1] = f2bf(f0.y); bp[2] = f2bf(f0.z); bp[3] = f2bf(f0.w);
        bp[4] = f2bf(f1.x); bp[5] = f2bf(f1.y); bp[6] = f2bf(f1.z); bp[7] = f2bf(f1.w);
    }

    float4v acc[17];
    #pragma unroll
    for (int c = 0; c < 17; c++) acc[c] = (float4v){0.f, 0.f, 0.f, 0.f};

    #pragma unroll
    for (int s = 0; s < 4; s++) {
        const unsigned short* fp = w1frag + (s * 64 + lane) * 8;
        #pragma unroll
        for (int c = 0; c < 17; c++) {
            short8 afrag = *(const short8*)(fp + c * 2048);
            acc[c] = __builtin_amdgcn_mfma_f32_16x16x32_bf16(afrag, bfr[s], acc[c], 0, 0, 0);
        }
    }

    int node = nb + m;
    #pragma unroll
    for (int c = 0; c < 16; c++) {
        unsigned pk = 0;
        pk = __builtin_amdgcn_cvt_pk_fp8_f32(acc[c][0], acc[c][1], pk, false);
        pk = __builtin_amdgcn_cvt_pk_fp8_f32(acc[c][2], acc[c][3], pk, true);
        *(unsigned*)(h1f8 + node * C1 + c * 16 + quad * 4) = pk;
    }
    *(float4*)(al1sd + node * 16 + quad * 4) =
        make_float4(acc[16][0], acc[16][1], acc[16][2], acc[16][3]);
    if (quad < 2) {   // src logits (rows 0-7) packed bf16
        uint2 pk;
        pk.x = (unsigned)f2bf(acc[16][0]) | ((unsigned)f2bf(acc[16][1]) << 16);
        pk.y = (unsigned)f2bf(acc[16][2]) | ((unsigned)f2bf(acc[16][3]) << 16);
        *(uint2*)(al1s8 + node * 8 + quad * 4) = pk;
    }
}

// ---------------------------------------------------------------------------
// agg1 (single launch): one wave per dst node, two-phase. Phase 1: lane e
// computes all 8 head-weights of edge e. Phase 2: 4 edges in flight,
// 256 B/edge fp8 gather, HW cvt_pk_f32_fp8 decode (2 ops / 4 channels).
// ---------------------------------------------------------------------------
__global__ __launch_bounds__(256) void k_agg1(const int* __restrict__ row_ptr,
                                              const int* __restrict__ esrc,
                                              const unsigned char* __restrict__ h1f8,
                                              const unsigned short* __restrict__ al1s8,
                                              const float* __restrict__ al1sd,
                                              const float* __restrict__ b1,
                                              unsigned short* __restrict__ helu_b) {
    __shared__ float wbuf[4][64 * 8];
    __shared__ int   sbuf[4][64];
    int wslot = threadIdx.x >> 6;
    int L = threadIdx.x & 63;
    int d = (blockIdx.x * 256 + threadIdx.x) >> 6;
    int h = L >> 3;
    int start = row_ptr[d], end = row_ptr[d + 1];
    float4 ald0 = *(const float4*)(al1sd + d * 16 + 8);
    float4 ald1 = *(const float4*)(al1sd + d * 16 + 12);
    float* wrow = wbuf[wslot];
    int* srow = sbuf[wslot];
    float denom = 0.f;
    float4 acc = make_float4(0.f, 0.f, 0.f, 0.f);
    const int Lofs = L * 4;

    for (int base = start; base < end; base += 64) {
        int cnt = min(64, end - base);
        int s = d;
        float wv0 = 0.f, wv1 = 0.f, wv2 = 0.f, wv3 = 0.f;
        float wv4 = 0.f, wv5 = 0.f, wv6 = 0.f, wv7 = 0.f;
        if (L < cnt) {
            s = esrc[base + L];
            uint4 as = *(const uint4*)(al1s8 + s * 8);
            float e;
            e = bflo(as.x) + ald0.x; e = e > 0.f ? e : 0.2f * e; wv0 = __expf(e);
            e = bfhi(as.x) + ald0.y; e = e > 0.f ? e : 0.2f * e; wv1 = __expf(e);
            e = bflo(as.y) + ald0.z; e = e > 0.f ? e : 0.2f * e; wv2 = __expf(e);
            e = bfhi(as.y) + ald0.w; e = e > 0.f ? e : 0.2f * e; wv3 = __expf(e);
            e = bflo(as.z) + ald1.x; e = e > 0.f ? e : 0.2f * e; wv4 = __expf(e);
            e = bfhi(as.z) + ald1.y; e = e > 0.f ? e : 0.2f * e; wv5 = __expf(e);
            e = bflo(as.w) + ald1.z; e = e > 0.f ? e : 0.2f * e; wv6 = __expf(e);
            e = bfhi(as.w) + ald1.w; e = e > 0.f ? e : 0.2f * e; wv7 = __expf(e);
        }
        srow[L] = s;
        *(float4*)&wrow[L * 8]     = make_float4(wv0, wv1, wv2, wv3);
        *(float4*)&wrow[L * 8 + 4] = make_float4(wv4, wv5, wv6, wv7);
        int cnt4 = (cnt + 3) & ~3;
        for (int i = 0; i < cnt4; i += 4) {
            int s0 = srow[i], s1 = srow[i + 1], s2 = srow[i + 2], s3 = srow[i + 3];
            float x0 = wrow[i * 8 + h];
            float x1 = wrow[i * 8 + 8 + h];
            float x2 = wrow[i * 8 + 16 + h];
            float x3 = wrow[i * 8 + 24 + h];
            unsigned v0 = *(const unsigned*)(h1f8 + s0 * C1 + Lofs);
            unsigned v1 = *(const unsigned*)(h1f8 + s1 * C1 + Lofs);
            unsigned v2 = *(const unsigned*)(h1f8 + s2 * C1 + Lofs);
            unsigned v3 = *(const unsigned*)(h1f8 + s3 * C1 + Lofs);
            denom += (x0 + x1) + (x2 + x3);
            float2v a, b;
            a = __builtin_amdgcn_cvt_pk_f32_fp8(v0, false);
            b = __builtin_amdgcn_cvt_pk_f32_fp8(v0, true);
            acc.x += x0 * a.x; acc.y += x0 * a.y; acc.z += x0 * b.x; acc.w += x0 * b.y;
            a = __builtin_amdgcn_cvt_pk_f32_fp8(v1, false);
            b = __builtin_amdgcn_cvt_pk_f32_fp8(v1, true);
            acc.x += x1 * a.x; acc.y += x1 * a.y; acc.z += x1 * b.x; acc.w += x1 * b.y;
            a = __builtin_amdgcn_cvt_pk_f32_fp8(v2, false);
            b = __builtin_amdgcn_cvt_pk_f32_fp8(v2, true);
            acc.x += x2 * a.x; acc.y += x2 * a.y; acc.z += x2 * b.x; acc.w += x2 * b.y;
            a = __builtin_amdgcn_cvt_pk_f32_fp8(v3, false);
            b = __builtin_amdgcn_cvt_pk_f32_fp8(v3, true);
            acc.x += x3 * a.x; acc.y += x3 * a.y; acc.z += x3 * b.x; acc.w += x3 * b.y;
        }
    }
    float inv = 1.0f / (denom + 1e-16f);
    float4 bv = *(const float4*)(b1 + Lofs);
    float o0 = acc.x * inv + bv.x;
    float o1 = acc.y * inv + bv.y;
    float o2 = acc.z * inv + bv.z;
    float o3 = acc.w * inv + bv.w;
    o0 = o0 > 0.f ? o0 : __expf(o0) - 1.0f;
    o1 = o1 > 0.f ? o1 : __expf(o1) - 1.0f;
    o2 = o2 > 0.f ? o2 : __expf(o2) - 1.0f;
    o3 = o3 > 0.f ? o3 : __expf(o3) - 1.0f;
    uint2 pk;
    pk.x = (unsigned)f2bf(o0) | ((unsigned)f2bf(o1) << 16);
    pk.y = (unsigned)f2bf(o2) | ((unsigned)f2bf(o3) << 16);
    *(uint2*)(helu_b + d * C1 + Lofs) = pk;
}

// ---------------------------------------------------------------------------
// GEMM2 via MFMA 16x16x32 bf16 + fused al2 epilogue (unchanged).
// ---------------------------------------------------------------------------
__global__ __launch_bounds__(256) void k_gemm2(const unsigned short* __restrict__ helu_b,
                                               const unsigned short* __restrict__ W2b,
                                               const float* __restrict__ a2s,
                                               const float* __restrict__ a2d,
                                               unsigned short* __restrict__ h2b,
                                               float* __restrict__ al2s,
                                               float* __restrict__ al2d) {
    int wid = (blockIdx.x * 256 + threadIdx.x) >> 6;
    int lane = threadIdx.x & 63;
    int nb = wid * 16;
    if (nb >= NN) return;
    int m = lane & 15, quad = lane >> 4;

    short8 bfrag[8];
    #pragma unroll
    for (int s = 0; s < 8; s++) {
        #pragma unroll
        for (int j = 0; j < 8; j++) {
            ((short*)&bfrag[s])[j] = (short)W2b[(s * 32 + quad * 8 + j) * DOUT + m];
        }
    }

    float4v acc = {0.f, 0.f, 0.f, 0.f};
    const unsigned short* arow = helu_b + (nb + m) * C1 + quad * 8;
    #pragma unroll
    for (int s = 0; s < 8; s++) {
        short8 afrag = *(const short8*)(arow + s * 32);
        acc = __builtin_amdgcn_mfma_f32_16x16x32_bf16(afrag, bfrag[s], acc, 0, 0, 0);
    }

    float as_c = a2s[m], ad_c = a2d[m];
    #pragma unroll
    for (int r = 0; r < 4; r++) {
        int node = nb + quad * 4 + r;
        float val = acc[r];
        h2b[node * DOUT + m] = f2bf(val);
        float ps = val * as_c;
        float pd = val * ad_c;
        ps += __shfl_xor(ps, 1, 64); ps += __shfl_xor(ps, 2, 64);
        ps += __shfl_xor(ps, 4, 64); ps += __shfl_xor(ps, 8, 64);
        pd += __shfl_xor(pd, 1, 64); pd += __shfl_xor(pd, 2, 64);
        pd += __shfl_xor(pd, 4, 64); pd += __shfl_xor(pd, 8, 64);
        if (m == 0) {
            al2s[node] = ps;
            al2d[node] = pd;
        }
    }
}

// ---------------------------------------------------------------------------
// agg2 + bias + log_softmax (unchanged two-phase).
// ---------------------------------------------------------------------------
__global__ __launch_bounds__(256) void k_agg2(const int* __restrict__ row_ptr,
                                              const int* __restrict__ esrc,
                                              const unsigned short* __restrict__ h2b,
                                              const float* __restrict__ al2s,
                                              const float* __restrict__ al2d,
                                              const float* __restrict__ b2,
                                              float* __restrict__ out) {
    __shared__ float wbuf2[4][64];
    __shared__ int   sbuf2[4][64];
    int wslot = threadIdx.x >> 6;
    int L = threadIdx.x & 63;
    int n = (blockIdx.x * 256 + threadIdx.x) >> 6;
    if (n >= NN) return;
    int c = L & 15, g = L >> 4;
    int start = row_ptr[n], end = row_ptr[n + 1];
    float ald = al2d[n];
    float* wrow = wbuf2[wslot];
    int* srow = sbuf2[wslot];
    float acc = 0.f, denom = 0.f;

    for (int base = start; base < end; base += 64) {
        int cnt = min(64, end - base);
        int s = n; float w = 0.f;
        if (L < cnt) {
            s = esrc[base + L];
            float e = al2s[s] + ald;
            e = e > 0.f ? e : 0.2f * e;
            w = __expf(e);
        }
        srow[L] = s;
        wrow[L] = w;
        int cnt4 = (cnt + 3) & ~3;
        for (int i = 0; i < cnt4; i += 4) {
            int idx = i + g;
            int ss = srow[idx];
            float ww = wrow[idx];
            float v = bf2f(h2b[ss * DOUT + c]);
            acc += ww * v;
            denom += ww;
        }
    }
    acc += __shfl_xor(acc, 16, 64);   acc += __shfl_xor(acc, 32, 64);
    denom += __shfl_xor(denom, 16, 64); denom += __shfl_xor(denom, 32, 64);
    float val = acc / (denom + 1e-16f) + b2[c];
    float m = val;
    #pragma unroll
    for (int mm = 1; mm < 16; mm <<= 1) m = fmaxf(m, __shfl_xor(m, mm, 64));
    float ex = __expf(val - m);
    float se = ex;
    #pragma unroll
    for (int mm = 1; mm < 16; mm <<= 1) se += __shfl_xor(se, mm, 64);
    if (L < 16) out[n * DOUT + c] = val - m - __logf(se);
}

// ---------------------------------------------------------------------------
extern "C" void kernel_launch(void* const* d_in, const int* in_sizes, int n_in,
                              void* d_out, int out_size, void* d_ws, size_t ws_size,
                              hipStream_t stream) {
    const float* x   = (const float*)d_in[0];
    const int*   ei  = (const int*)d_in[1];
    const float* W1  = (const float*)d_in[2];
    const float* a1s = (const float*)d_in[3];
    const float* a1d = (const float*)d_in[4];
    const float* b1  = (const float*)d_in[5];
    const float* W2  = (const float*)d_in[6];
    const float* a2s = (const float*)d_in[7];
    const float* a2d = (const float*)d_in[8];
    const float* b2  = (const float*)d_in[9];
    float* outp = (float*)d_out;

    // workspace layout
    unsigned char* h1f8    = (unsigned char*)d_ws;       // N*256 fp8 e4m3 (12.8 MB)
    unsigned short* helu_b = (unsigned short*)(h1f8 + NN * C1);  // N*256 bf16
    unsigned short* h2b    = helu_b + NN * C1;           // N*16 bf16
    unsigned short* W2b    = h2b + NN * DOUT;            // 4096 bf16
    unsigned short* w1frag = W2b + C1 * DOUT;            // 34816 bf16
    unsigned short* al1s8  = w1frag + 17 * 2048;         // N*8 bf16 (src logits)
    float* al1sd = (float*)(al1s8 + NN * 8);             // N*16 fp32
    float* al2sb = al1sd + NN * 16;                      // N
    float* al2db = al2sb + NN;                           // N
    int* row_ptr = (int*)(al2db + NN);                   // N+1
    int* esrc    = row_ptr + NN + 1;                     // EP
    int* cntb    = esrc + EP;                            // NB
    // ebuf aliases helu_b (25.6 MB >= 12.85 MB needed); consumed by k_csr
    // before agg1 writes helu_b -- single-stream ordering guarantees safety.
    int2* ebuf   = (int2*)helu_b;                        // NB * CAP int2

    hipMemsetAsync(cntb, 0, NB * sizeof(int), stream);
    k_bucketA<<<(EP + BBLK - 1) / BBLK, 256, 0, stream>>>(ei, cntb, ebuf);
    k_csr<<<NB, 1024, 0, stream>>>(cntb, ebuf, row_ptr, esrc);

    k_prepfw<<<(17 * 2048 + C1 * DOUT + 255) / 256, 256, 0, stream>>>(W1, a1s, a1d, W2, w1frag, W2b);
    k_gemm1<<<(NW1 * 64 + 255) / 256, 256, 0, stream>>>(x, w1frag, h1f8, al1sd, al1s8);
    k_agg1<<<12500, 256, 0, stream>>>(row_ptr, esrc, h1f8, al1s8, al1sd, b1, helu_b);

    k_gemm2<<<(NW1 * 64 + 255) / 256, 256, 0, stream>>>(helu_b, W2b, a2s, a2d, h2b, al2sb, al2db);
    k_agg2<<<(NN * 64 + 255) / 256, 256, 0, stream>>>(row_ptr, esrc, h2b, al2sb, al2db, b2, outp);
}

// Round 13
// 212.565 us; speedup vs baseline: 1.9955x; 1.0041x over previous
//
#include <hip/hip_runtime.h>
#include <hip/hip_bf16.h>

// Problem constants (match reference)
#define NN 50000
#define EE 800000
#define EP (EE + NN)        // edges + self loops = 850000
#define DIN 128
#define HID 32
#define HEADS 8
#define C1 (HEADS * HID)    // 256
#define DOUT 16
#define NW1 3125            // gemm1/gemm2 waves: 50000/16
#define SH 9                // bucket shift: 512 nodes/bucket
#define NB 98               // ceil(50000/512)
#define CAP 16384           // per-bucket ebuf capacity (mean 8704, sigma~90)
#define EPT 8               // edges per thread in k_bucketA
#define BBLK (256 * EPT)    // 2048 edges per block

typedef __attribute__((ext_vector_type(8))) short short8;   // 8 bf16 (4 VGPRs)
typedef __attribute__((ext_vector_type(4))) float float4v;  // MFMA C/D
typedef __attribute__((ext_vector_type(2))) float float2v;  // fp8 cvt result

__device__ inline unsigned short f2bf(float f) {
    __hip_bfloat16 b = __float2bfloat16(f);
    return *reinterpret_cast<unsigned short*>(&b);
}
__device__ inline float bf2f(unsigned short u) {
    union { unsigned int i; float f; } x;
    x.i = ((unsigned int)u) << 16;
    return x.f;
}
__device__ inline float bflo(unsigned u) {
    union { unsigned int i; float f; } x;
    x.i = u << 16;
    return x.f;
}
__device__ inline float bfhi(unsigned u) {
    union { unsigned int i; float f; } x;
    x.i = u & 0xffff0000u;
    return x.f;
}

// ---------------------------------------------------------------------------
// CSR pass 1: bucket edges by dst>>9 into per-bucket regions of ebuf.
// Per-wave LDS histograms (4 copies) cut same-address atomic serialization
// ~4x vs a single shared histogram (same-address LDS atomics serialize).
// ---------------------------------------------------------------------------
__global__ __launch_bounds__(256) void k_bucketA(const int* __restrict__ ei,
                                                 int* __restrict__ cntb,
                                                 int2* __restrict__ ebuf) {
    __shared__ int hist[4][NB];
    __shared__ int base[4][NB];
    int t = threadIdx.x;
    int wave = t >> 6;
    for (int i = t; i < 4 * NB; i += 256) ((int*)hist)[i] = 0;
    __syncthreads();
    int e0 = blockIdx.x * BBLK;
    int s[EPT], d[EPT], r[EPT];
    #pragma unroll
    for (int j = 0; j < EPT; j++) {
        int e = e0 + j * 256 + t;
        int ss = 0, dd = -1;
        if (e < EE) { ss = ei[e]; dd = ei[EE + e]; }
        else if (e < EP) { ss = e - EE; dd = ss; }   // self loop
        s[j] = ss; d[j] = dd;
        if (dd >= 0) r[j] = atomicAdd(&hist[wave][dd >> SH], 1);
    }
    __syncthreads();
    if (t < NB) {
        int h0 = hist[0][t], h1 = hist[1][t], h2 = hist[2][t], h3 = hist[3][t];
        int tot = h0 + h1 + h2 + h3;
        int bb = tot ? atomicAdd(&cntb[t], tot) : 0;
        base[0][t] = bb;
        base[1][t] = bb + h0;
        base[2][t] = bb + h0 + h1;
        base[3][t] = bb + h0 + h1 + h2;
    }
    __syncthreads();
    #pragma unroll
    for (int j = 0; j < EPT; j++) {
        if (d[j] >= 0) {
            int b = d[j] >> SH;
            ebuf[b * CAP + base[wave][b] + r[j]] = make_int2(s[j], d[j]);
        }
    }
}

// ---------------------------------------------------------------------------
// CSR pass 2: one block per bucket; LDS count -> scan -> rank scatter.
// ---------------------------------------------------------------------------
__global__ __launch_bounds__(1024) void k_csr(const int* __restrict__ cntb,
                                              const int2* __restrict__ ebuf,
                                              int* __restrict__ row_ptr,
                                              int* __restrict__ esrc) {
    __shared__ int sdeg[512];
    __shared__ int wtot[8];
    __shared__ int bpart[2];
    int b = blockIdx.x;
    int t = threadIdx.x;
    int lane = t & 63, wave = t >> 6;
    int nodes0 = b << SH;
    if (t < 512) sdeg[t] = 0;
    if (t < 128) {
        int v = (t < b) ? cntb[t] : 0;
        #pragma unroll
        for (int off = 1; off < 64; off <<= 1) v += __shfl_xor(v, off, 64);
        if (lane == 0) bpart[wave] = v;
    }
    __syncthreads();
    int baseS = bpart[0] + bpart[1];
    int cnt = cntb[b];
    const int2* eb = ebuf + b * CAP;
    for (int i = t; i < cnt; i += 1024)
        atomicAdd(&sdeg[eb[i].y & 511], 1);
    __syncthreads();
    int v = (t < 512) ? sdeg[t] : 0;
    int inc = v;
    #pragma unroll
    for (int off = 1; off < 64; off <<= 1) {
        int u = __shfl_up(inc, off, 64);
        if (lane >= off) inc += u;
    }
    if (t < 512 && lane == 63) wtot[wave] = inc;
    __syncthreads();
    if (wave == 0 && lane < 8) {
        int w = wtot[lane];
        int iw = w;
        #pragma unroll
        for (int off = 1; off < 8; off <<= 1) {
            int u = __shfl_up(iw, off, 64);
            if (lane >= off) iw += u;
        }
        wtot[lane] = iw - w;   // exclusive
    }
    __syncthreads();
    int excl = inc - v + ((t < 512) ? wtot[wave] : 0);
    __syncthreads();
    if (t < 512) {
        sdeg[t] = excl;
        int node = nodes0 + t;
        if (node < NN) row_ptr[node] = baseS + excl;
    }
    __syncthreads();
    for (int i = t; i < cnt; i += 1024) {
        int2 e = eb[i];
        int pos = atomicAdd(&sdeg[e.y & 511], 1);
        esrc[baseS + pos] = e.x;
    }
    if (b == 0 && t == 0) row_ptr[NN] = EP;
}

// ---------------------------------------------------------------------------
// prep: gemm1 A-fragment image (17 tiles) + gemm2 B-fragment image (w2frag,
// fragment-order: one short8 load per K-step instead of 64 scalar loads).
// ---------------------------------------------------------------------------
__global__ void k_prepfw(const float* __restrict__ W1, const float* __restrict__ a1s,
                         const float* __restrict__ a1d, const float* __restrict__ W2,
                         unsigned short* __restrict__ w1frag,
                         unsigned short* __restrict__ w2frag) {
    int i = blockIdx.x * 256 + threadIdx.x;
    if (i < 17 * 2048) {
        int j = i & 7, lane = (i >> 3) & 63, s = (i >> 9) & 3, c = i >> 11;
        int q = lane >> 4, m = lane & 15;
        int k = s * 32 + q * 8 + j;
        float val;
        if (c < 16) {
            val = W1[k * C1 + c * 16 + m];
        } else {
            int h = m & 7;
            const float* av = (m < 8) ? a1s : a1d;
            float acc = 0.f;
            #pragma unroll
            for (int j2 = 0; j2 < 32; j2++)
                acc += W1[k * C1 + h * 32 + j2] * av[h * 32 + j2];
            val = acc;
        }
        w1frag[i] = f2bf(val);
    } else if (i < 17 * 2048 + 8 * 512) {
        int j2 = i - 17 * 2048;               // 0..4095
        int jj = j2 & 7, lane = (j2 >> 3) & 63, s = j2 >> 9;   // s = K-step 0..7
        int q = lane >> 4, m = lane & 15;
        w2frag[j2] = f2bf(W2[(s * 32 + q * 8 + jj) * DOUT + m]);
    }
}

// ---------------------------------------------------------------------------
// GEMM1 via MFMA (operand-swapped). Epilogue: h1 gather table stored as
// FP8 e4m3 + al1sd fp32 [node][16] + packed bf16 al1s8[node][8].
// ---------------------------------------------------------------------------
__global__ __launch_bounds__(256) void k_gemm1(const float* __restrict__ x,
                                               const unsigned short* __restrict__ w1frag,
                                               unsigned char* __restrict__ h1f8,
                                               float* __restrict__ al1sd,
                                               unsigned short* __restrict__ al1s8) {
    int wid = (blockIdx.x * 256 + threadIdx.x) >> 6;
    int lane = threadIdx.x & 63;
    if (wid >= NW1) return;
    int nb = wid * 16;
    int m = lane & 15, quad = lane >> 4;
    const float* xrow = x + (nb + m) * DIN;

    float4 xf[8];
    #pragma unroll
    for (int s = 0; s < 4; s++) {
        xf[2 * s]     = *(const float4*)(xrow + s * 32 + quad * 8);
        xf[2 * s + 1] = *(const float4*)(xrow + s * 32 + quad * 8 + 4);
    }
    short8 bfr[4];
    #pragma unroll
    for (int s = 0; s < 4; s++) {
        unsigned short* bp = (unsigned short*)&bfr[s];
        float4 f0 = xf[2 * s], f1 = xf[2 * s + 1];
        bp[0] = f2bf(f0.x); bp[1] = f2bf(f0.y); bp[2] = f2bf(f0.z); bp[3] = f2bf(f0.w);
        bp[4] = f2bf(f1.x); bp[5] = f2bf(f1.y); bp[6] = f2bf(f1.z); bp[7] = f2bf(f1.w);
    }

    float4v acc[17];
    #pragma unroll
    for (int c = 0; c < 17; c++) acc[c] = (float4v){0.f, 0.f, 0.f, 0.f};

    #pragma unroll
    for (int s = 0; s < 4; s++) {
        const unsigned short* fp = w1frag + (s * 64 + lane) * 8;
        #pragma unroll
        for (int c = 0; c < 17; c++) {
            short8 afrag = *(const short8*)(fp + c * 2048);
            acc[c] = __builtin_amdgcn_mfma_f32_16x16x32_bf16(afrag, bfr[s], acc[c], 0, 0, 0);
        }
    }

    int node = nb + m;
    #pragma unroll
    for (int c = 0; c < 16; c++) {
        unsigned pk = 0;
        pk = __builtin_amdgcn_cvt_pk_fp8_f32(acc[c][0], acc[c][1], pk, false);
        pk = __builtin_amdgcn_cvt_pk_fp8_f32(acc[c][2], acc[c][3], pk, true);
        *(unsigned*)(h1f8 + node * C1 + c * 16 + quad * 4) = pk;
    }
    *(float4*)(al1sd + node * 16 + quad * 4) =
        make_float4(acc[16][0], acc[16][1], acc[16][2], acc[16][3]);
    if (quad < 2) {   // src logits (rows 0-7) packed bf16
        uint2 pk;
        pk.x = (unsigned)f2bf(acc[16][0]) | ((unsigned)f2bf(acc[16][1]) << 16);
        pk.y = (unsigned)f2bf(acc[16][2]) | ((unsigned)f2bf(acc[16][3]) << 16);
        *(uint2*)(al1s8 + node * 8 + quad * 4) = pk;
    }
}

// ---------------------------------------------------------------------------
// agg1 (single launch): one wave per dst node, two-phase, fp8 gather.
// ---------------------------------------------------------------------------
__global__ __launch_bounds__(256) void k_agg1(const int* __restrict__ row_ptr,
                                              const int* __restrict__ esrc,
                                              const unsigned char* __restrict__ h1f8,
                                              const unsigned short* __restrict__ al1s8,
                                              const float* __restrict__ al1sd,
                                              const float* __restrict__ b1,
                                              unsigned short* __restrict__ helu_b) {
    __shared__ float wbuf[4][64 * 8];
    __shared__ int   sbuf[4][64];
    int wslot = threadIdx.x >> 6;
    int L = threadIdx.x & 63;
    int d = (blockIdx.x * 256 + threadIdx.x) >> 6;
    int h = L >> 3;
    int start = row_ptr[d], end = row_ptr[d + 1];
    float4 ald0 = *(const float4*)(al1sd + d * 16 + 8);
    float4 ald1 = *(const float4*)(al1sd + d * 16 + 12);
    float* wrow = wbuf[wslot];
    int* srow = sbuf[wslot];
    float denom = 0.f;
    float4 acc = make_float4(0.f, 0.f, 0.f, 0.f);
    const int Lofs = L * 4;

    for (int base = start; base < end; base += 64) {
        int cnt = min(64, end - base);
        int s = d;
        float wv0 = 0.f, wv1 = 0.f, wv2 = 0.f, wv3 = 0.f;
        float wv4 = 0.f, wv5 = 0.f, wv6 = 0.f, wv7 = 0.f;
        if (L < cnt) {
            s = esrc[base + L];
            uint4 as = *(const uint4*)(al1s8 + s * 8);
            float e;
            e = bflo(as.x) + ald0.x; e = e > 0.f ? e : 0.2f * e; wv0 = __expf(e);
            e = bfhi(as.x) + ald0.y; e = e > 0.f ? e : 0.2f * e; wv1 = __expf(e);
            e = bflo(as.y) + ald0.z; e = e > 0.f ? e : 0.2f * e; wv2 = __expf(e);
            e = bfhi(as.y) + ald0.w; e = e > 0.f ? e : 0.2f * e; wv3 = __expf(e);
            e = bflo(as.z) + ald1.x; e = e > 0.f ? e : 0.2f * e; wv4 = __expf(e);
            e = bfhi(as.z) + ald1.y; e = e > 0.f ? e : 0.2f * e; wv5 = __expf(e);
            e = bflo(as.w) + ald1.z; e = e > 0.f ? e : 0.2f * e; wv6 = __expf(e);
            e = bfhi(as.w) + ald1.w; e = e > 0.f ? e : 0.2f * e; wv7 = __expf(e);
        }
        srow[L] = s;
        *(float4*)&wrow[L * 8]     = make_float4(wv0, wv1, wv2, wv3);
        *(float4*)&wrow[L * 8 + 4] = make_float4(wv4, wv5, wv6, wv7);
        int cnt4 = (cnt + 3) & ~3;
        for (int i = 0; i < cnt4; i += 4) {
            int s0 = srow[i], s1 = srow[i + 1], s2 = srow[i + 2], s3 = srow[i + 3];
            float x0 = wrow[i * 8 + h];
            float x1 = wrow[i * 8 + 8 + h];
            float x2 = wrow[i * 8 + 16 + h];
            float x3 = wrow[i * 8 + 24 + h];
            unsigned v0 = *(const unsigned*)(h1f8 + s0 * C1 + Lofs);
            unsigned v1 = *(const unsigned*)(h1f8 + s1 * C1 + Lofs);
            unsigned v2 = *(const unsigned*)(h1f8 + s2 * C1 + Lofs);
            unsigned v3 = *(const unsigned*)(h1f8 + s3 * C1 + Lofs);
            denom += (x0 + x1) + (x2 + x3);
            float2v a, b;
            a = __builtin_amdgcn_cvt_pk_f32_fp8(v0, false);
            b = __builtin_amdgcn_cvt_pk_f32_fp8(v0, true);
            acc.x += x0 * a.x; acc.y += x0 * a.y; acc.z += x0 * b.x; acc.w += x0 * b.y;
            a = __builtin_amdgcn_cvt_pk_f32_fp8(v1, false);
            b = __builtin_amdgcn_cvt_pk_f32_fp8(v1, true);
            acc.x += x1 * a.x; acc.y += x1 * a.y; acc.z += x1 * b.x; acc.w += x1 * b.y;
            a = __builtin_amdgcn_cvt_pk_f32_fp8(v2, false);
            b = __builtin_amdgcn_cvt_pk_f32_fp8(v2, true);
            acc.x += x2 * a.x; acc.y += x2 * a.y; acc.z += x2 * b.x; acc.w += x2 * b.y;
            a = __builtin_amdgcn_cvt_pk_f32_fp8(v3, false);
            b = __builtin_amdgcn_cvt_pk_f32_fp8(v3, true);
            acc.x += x3 * a.x; acc.y += x3 * a.y; acc.z += x3 * b.x; acc.w += x3 * b.y;
        }
    }
    float inv = 1.0f / (denom + 1e-16f);
    float4 bv = *(const float4*)(b1 + Lofs);
    float o0 = acc.x * inv + bv.x;
    float o1 = acc.y * inv + bv.y;
    float o2 = acc.z * inv + bv.z;
    float o3 = acc.w * inv + bv.w;
    o0 = o0 > 0.f ? o0 : __expf(o0) - 1.0f;
    o1 = o1 > 0.f ? o1 : __expf(o1) - 1.0f;
    o2 = o2 > 0.f ? o2 : __expf(o2) - 1.0f;
    o3 = o3 > 0.f ? o3 : __expf(o3) - 1.0f;
    uint2 pk;
    pk.x = (unsigned)f2bf(o0) | ((unsigned)f2bf(o1) << 16);
    pk.y = (unsigned)f2bf(o2) | ((unsigned)f2bf(o3) << 16);
    *(uint2*)(helu_b + d * C1 + Lofs) = pk;
}

// ---------------------------------------------------------------------------
// GEMM2 via MFMA + fused al2 epilogue. B-fragments now one short8 load per
// K-step from the prepped w2frag image (was 64 scalar loads per step).
// ---------------------------------------------------------------------------
__global__ __launch_bounds__(256) void k_gemm2(const unsigned short* __restrict__ helu_b,
                                               const unsigned short* __restrict__ w2frag,
                                               const float* __restrict__ a2s,
                                               const float* __restrict__ a2d,
                                               unsigned short* __restrict__ h2b,
                                               float* __restrict__ al2s,
                                               float* __restrict__ al2d) {
    int wid = (blockIdx.x * 256 + threadIdx.x) >> 6;
    int lane = threadIdx.x & 63;
    int nb = wid * 16;
    if (nb >= NN) return;
    int m = lane & 15, quad = lane >> 4;

    const unsigned short* wp2 = w2frag + lane * 8;
    float4v acc = {0.f, 0.f, 0.f, 0.f};
    const unsigned short* arow = helu_b + (nb + m) * C1 + quad * 8;
    #pragma unroll
    for (int s = 0; s < 8; s++) {
        short8 afrag = *(const short8*)(arow + s * 32);
        short8 bfrag = *(const short8*)(wp2 + s * 512);
        acc = __builtin_amdgcn_mfma_f32_16x16x32_bf16(afrag, bfrag, acc, 0, 0, 0);
    }

    float as_c = a2s[m], ad_c = a2d[m];
    #pragma unroll
    for (int r = 0; r < 4; r++) {
        int node = nb + quad * 4 + r;
        float val = acc[r];
        h2b[node * DOUT + m] = f2bf(val);
        float ps = val * as_c;
        float pd = val * ad_c;
        ps += __shfl_xor(ps, 1, 64); ps += __shfl_xor(ps, 2, 64);
        ps += __shfl_xor(ps, 4, 64); ps += __shfl_xor(ps, 8, 64);
        pd += __shfl_xor(pd, 1, 64); pd += __shfl_xor(pd, 2, 64);
        pd += __shfl_xor(pd, 4, 64); pd += __shfl_xor(pd, 8, 64);
        if (m == 0) {
            al2s[node] = ps;
            al2d[node] = pd;
        }
    }
}

// ---------------------------------------------------------------------------
// agg2 + bias + log_softmax (unchanged two-phase).
// ---------------------------------------------------------------------------
__global__ __launch_bounds__(256) void k_agg2(const int* __restrict__ row_ptr,
                                              const int* __restrict__ esrc,
                                              const unsigned short* __restrict__ h2b,
                                              const float* __restrict__ al2s,
                                              const float* __restrict__ al2d,
                                              const float* __restrict__ b2,
                                              float* __restrict__ out) {
    __shared__ float wbuf2[4][64];
    __shared__ int   sbuf2[4][64];
    int wslot = threadIdx.x >> 6;
    int L = threadIdx.x & 63;
    int n = (blockIdx.x * 256 + threadIdx.x) >> 6;
    if (n >= NN) return;
    int c = L & 15, g = L >> 4;
    int start = row_ptr[n], end = row_ptr[n + 1];
    float ald = al2d[n];
    float* wrow = wbuf2[wslot];
    int* srow = sbuf2[wslot];
    float acc = 0.f, denom = 0.f;

    for (int base = start; base < end; base += 64) {
        int cnt = min(64, end - base);
        int s = n; float w = 0.f;
        if (L < cnt) {
            s = esrc[base + L];
            float e = al2s[s] + ald;
            e = e > 0.f ? e : 0.2f * e;
            w = __expf(e);
        }
        srow[L] = s;
        wrow[L] = w;
        int cnt4 = (cnt + 3) & ~3;
        for (int i = 0; i < cnt4; i += 4) {
            int idx = i + g;
            int ss = srow[idx];
            float ww = wrow[idx];
            float v = bf2f(h2b[ss * DOUT + c]);
            acc += ww * v;
            denom += ww;
        }
    }
    acc += __shfl_xor(acc, 16, 64);   acc += __shfl_xor(acc, 32, 64);
    denom += __shfl_xor(denom, 16, 64); denom += __shfl_xor(denom, 32, 64);
    float val = acc / (denom + 1e-16f) + b2[c];
    float m = val;
    #pragma unroll
    for (int mm = 1; mm < 16; mm <<= 1) m = fmaxf(m, __shfl_xor(m, mm, 64));
    float ex = __expf(val - m);
    float se = ex;
    #pragma unroll
    for (int mm = 1; mm < 16; mm <<= 1) se += __shfl_xor(se, mm, 64);
    if (L < 16) out[n * DOUT + c] = val - m - __logf(se);
}

// ---------------------------------------------------------------------------
extern "C" void kernel_launch(void* const* d_in, const int* in_sizes, int n_in,
                              void* d_out, int out_size, void* d_ws, size_t ws_size,
                              hipStream_t stream) {
    const float* x   = (const float*)d_in[0];
    const int*   ei  = (const int*)d_in[1];
    const float* W1  = (const float*)d_in[2];
    const float* a1s = (const float*)d_in[3];
    const float* a1d = (const float*)d_in[4];
    const float* b1  = (const float*)d_in[5];
    const float* W2  = (const float*)d_in[6];
    const float* a2s = (const float*)d_in[7];
    const float* a2d = (const float*)d_in[8];
    const float* b2  = (const float*)d_in[9];
    float* outp = (float*)d_out;

    // workspace layout
    unsigned char* h1f8    = (unsigned char*)d_ws;       // N*256 fp8 e4m3 (12.8 MB)
    unsigned short* helu_b = (unsigned short*)(h1f8 + NN * C1);  // N*256 bf16
    unsigned short* h2b    = helu_b + NN * C1;           // N*16 bf16
    unsigned short* w2frag = h2b + NN * DOUT;            // 4096 bf16 (frag order)
    unsigned short* w1frag = w2frag + 8 * 512;           // 34816 bf16
    unsigned short* al1s8  = w1frag + 17 * 2048;         // N*8 bf16 (src logits)
    float* al1sd = (float*)(al1s8 + NN * 8);             // N*16 fp32
    float* al2sb = al1sd + NN * 16;                      // N
    float* al2db = al2sb + NN;                           // N
    int* row_ptr = (int*)(al2db + NN);                   // N+1
    int* esrc    = row_ptr + NN + 1;                     // EP
    int* cntb    = esrc + EP;                            // NB
    // ebuf aliases helu_b (25.6 MB >= 12.85 MB needed); consumed by k_csr
    // before agg1 writes helu_b -- single-stream ordering guarantees safety.
    int2* ebuf   = (int2*)helu_b;                        // NB * CAP int2

    hipMemsetAsync(cntb, 0, NB * sizeof(int), stream);
    k_bucketA<<<(EP + BBLK - 1) / BBLK, 256, 0, stream>>>(ei, cntb, ebuf);
    k_csr<<<NB, 1024, 0, stream>>>(cntb, ebuf, row_ptr, esrc);

    k_prepfw<<<(17 * 2048 + 8 * 512 + 255) / 256, 256, 0, stream>>>(W1, a1s, a1d, W2, w1frag, w2frag);
    k_gemm1<<<(NW1 * 64 + 255) / 256, 256, 0, stream>>>(x, w1frag, h1f8, al1sd, al1s8);
    k_agg1<<<12500, 256, 0, stream>>>(row_ptr, esrc, h1f8, al1s8, al1sd, b1, helu_b);

    k_gemm2<<<(NW1 * 64 + 255) / 256, 256, 0, stream>>>(helu_b, w2frag, a2s, a2d, h2b, al2sb, al2db);
    k_agg2<<<(NN * 64 + 255) / 256, 256, 0, stream>>>(row_ptr, esrc, h2b, al2sb, al2db, b2, outp);
}